// Round 10
// baseline (255.814 us; speedup 1.0000x reference)
//
#include <hip/hip_runtime.h>
#include <hip/hip_bf16.h>
#include <math.h>
#include <stdint.h>

// Problem constants
constexpr int Bn = 4, Tn = 1024, Cn = 1024, Hn = 16;
constexpr int BT = Bn * Tn;                 // 4096
constexpr long long BTC = (long long)BT * Cn;  // 4M elements
constexpr int CL = 64;                      // chunk length
constexpr int NC = Tn / CL;                 // 16 chunks

typedef __bf16 bf16x8_t __attribute__((ext_vector_type(8)));
typedef float f32x4_t __attribute__((ext_vector_type(4)));
typedef unsigned short us8_t __attribute__((ext_vector_type(8)));

__device__ __forceinline__ unsigned short f2bf_bits(float v) {
    __hip_bfloat16 h = __float2bfloat16(v);
    return *reinterpret_cast<unsigned short*>(&h);
}

// Direct global->LDS 16B/lane (wave-uniform LDS base + lane*16). CK-style casts.
__device__ __forceinline__ void gload16(const void* g, void* l) {
    auto const* gp = reinterpret_cast<const unsigned int __attribute__((address_space(1)))*>(
        reinterpret_cast<uintptr_t>(g));
    auto* lp = reinterpret_cast<unsigned int __attribute__((address_space(3)))*>(
        reinterpret_cast<uintptr_t>(l));
    __builtin_amdgcn_global_load_lds(gp, lp, 16, 0, 0);
}

// ---------------------------------------------------------------------------
// mix input for the token-mix LoRA (x4 vectorized)
// ---------------------------------------------------------------------------
__global__ __launch_bounds__(256) void prep_mixin(const float* __restrict__ x,
                                                  const float* __restrict__ x_maa,
                                                  __hip_bfloat16* __restrict__ out) {
    long long q = (long long)blockIdx.x * 256 + threadIdx.x;   // quad index
    if (q * 4 >= BTC) return;
    long long idx = q * 4;
    int c = (int)(idx & (Cn - 1));
    long long bt = idx >> 10;
    int t = (int)(bt & (Tn - 1));
    float4 xv = *reinterpret_cast<const float4*>(x + idx);
    float4 xp = (t > 0) ? *reinterpret_cast<const float4*>(x + idx - Cn)
                        : make_float4(0.f, 0.f, 0.f, 0.f);
    float4 ma = *reinterpret_cast<const float4*>(x_maa + c);
    ushort4 o;
    o.x = f2bf_bits(xv.x + (xp.x - xv.x) * ma.x);
    o.y = f2bf_bits(xv.y + (xp.y - xv.y) * ma.y);
    o.z = f2bf_bits(xv.z + (xp.z - xv.z) * ma.z);
    o.w = f2bf_bits(xv.w + (xp.w - xv.w) * ma.w);
    *reinterpret_cast<ushort4*>(out + idx) = o;
}

// ---------------------------------------------------------------------------
// Transpose + convert, 5 square weights in one dispatch (z selects matrix).
// ---------------------------------------------------------------------------
__global__ __launch_bounds__(256) void transp5(const float* __restrict__ W0,
                                               const float* __restrict__ W1,
                                               const float* __restrict__ W2,
                                               const float* __restrict__ W3,
                                               const float* __restrict__ W4,
                                               __hip_bfloat16* __restrict__ T0,
                                               __hip_bfloat16* __restrict__ T1,
                                               __hip_bfloat16* __restrict__ T2,
                                               __hip_bfloat16* __restrict__ T3,
                                               __hip_bfloat16* __restrict__ T4) {
    int z = blockIdx.z;
    const float* W = (z == 0) ? W0 : (z == 1) ? W1 : (z == 2) ? W2 : (z == 3) ? W3 : W4;
    __hip_bfloat16* Wt = (z == 0) ? T0 : (z == 1) ? T1 : (z == 2) ? T2 : (z == 3) ? T3 : T4;
    __shared__ float tile[32][33];
    int c0 = blockIdx.x * 32, r0 = blockIdx.y * 32;
    int tx = threadIdx.x & 31, ty = threadIdx.x >> 5;
    #pragma unroll
    for (int i = 0; i < 4; i++)
        tile[ty + 8 * i][tx] = W[(size_t)(r0 + ty + 8 * i) * Cn + c0 + tx];
    __syncthreads();
    #pragma unroll
    for (int i = 0; i < 4; i++)
        Wt[(size_t)(c0 + ty + 8 * i) * Cn + r0 + tx] = __float2bfloat16(tile[tx][ty + 8 * i]);
}

// Generic single transpose (tm_w1: [Cn,160] -> [160,Cn])
__global__ __launch_bounds__(256) void transp_bf16(const float* __restrict__ W,
                                                   __hip_bfloat16* __restrict__ Wt,
                                                   int R, int Cc) {
    __shared__ float tile[32][33];
    int c0 = blockIdx.x * 32, r0 = blockIdx.y * 32;
    int tx = threadIdx.x & 31, ty = threadIdx.x >> 5;
    #pragma unroll
    for (int i = 0; i < 4; i++)
        tile[ty + 8 * i][tx] = W[(size_t)(r0 + ty + 8 * i) * Cc + c0 + tx];
    __syncthreads();
    #pragma unroll
    for (int i = 0; i < 4; i++)
        Wt[(size_t)(c0 + ty + 8 * i) * R + r0 + tx] = __float2bfloat16(tile[tx][ty + 8 * i]);
}

// ---------------------------------------------------------------------------
// f32 tiled GEMM (decay LoRA GEMM2, precision-sensitive): C = A[M,K]@B[K,N].
// EPI: 3 logdecay (-exp(extra[col]+acc))
// ---------------------------------------------------------------------------
template <int EPI>
__global__ __launch_bounds__(256) void gemm_f32(const float* __restrict__ A,
                                                const float* __restrict__ Bm,
                                                float* __restrict__ C,
                                                int M, int N, int K,
                                                const float* __restrict__ extra) {
    __shared__ float As[16][64];
    __shared__ float Bs[16][64];
    int tid = threadIdx.x;
    int m0 = blockIdx.y * 64, n0 = blockIdx.x * 64;
    int tx = tid & 15, ty = tid >> 4;
    int ar = tid >> 2, ac = (tid & 3) * 4;
    int br = tid >> 4, bc = (tid & 15) * 4;
    float acc[4][4] = {};

    for (int k0 = 0; k0 < K; k0 += 16) {
        const float* ap = A + (size_t)(m0 + ar) * K + k0 + ac;
        float4 av = *reinterpret_cast<const float4*>(ap);
        As[ac + 0][ar] = av.x; As[ac + 1][ar] = av.y;
        As[ac + 2][ar] = av.z; As[ac + 3][ar] = av.w;
        float4 bv = *reinterpret_cast<const float4*>(Bm + (size_t)(k0 + br) * N + n0 + bc);
        *reinterpret_cast<float4*>(&Bs[br][bc]) = bv;
        __syncthreads();
        #pragma unroll
        for (int kk = 0; kk < 16; kk++) {
            float4 a4 = *reinterpret_cast<const float4*>(&As[kk][ty * 4]);
            float4 b4 = *reinterpret_cast<const float4*>(&Bs[kk][tx * 4]);
            float aa[4] = {a4.x, a4.y, a4.z, a4.w};
            float bb[4] = {b4.x, b4.y, b4.z, b4.w};
            #pragma unroll
            for (int i = 0; i < 4; i++)
                #pragma unroll
                for (int j = 0; j < 4; j++)
                    acc[i][j] = fmaf(aa[i], bb[j], acc[i][j]);
        }
        __syncthreads();
    }

    #pragma unroll
    for (int i = 0; i < 4; i++) {
        int row = m0 + ty * 4 + i;
        #pragma unroll
        for (int j = 0; j < 4; j++) {
            int col = n0 + tx * 4 + j;
            float v = acc[i][j];
            if (EPI == 3) v = -expf(extra[col] + v);
            C[(size_t)row * N + col] = v;
        }
    }
}

// ---------------------------------------------------------------------------
// Split-K f32 GEMM for the decay LoRA1 ([4096,1024]@[1024,64], N==64).
// ---------------------------------------------------------------------------
template <int KS>
__global__ __launch_bounds__(256) void gemm_f32_splitk(const float* __restrict__ A,
                                                       const float* __restrict__ Bm,
                                                       float* __restrict__ part,
                                                       int M, int N, int K) {
    __shared__ float As[16][64];
    __shared__ float Bs[16][64];
    int tid = threadIdx.x;
    int kp = blockIdx.x;
    int m0 = blockIdx.y * 64;
    int kbeg = kp * (K / KS), kend = kbeg + K / KS;
    int tx = tid & 15, ty = tid >> 4;
    int ar = tid >> 2, ac = (tid & 3) * 4;
    int br = tid >> 4, bc = (tid & 15) * 4;
    float acc[4][4] = {};

    for (int k0 = kbeg; k0 < kend; k0 += 16) {
        float4 av = *reinterpret_cast<const float4*>(A + (size_t)(m0 + ar) * K + k0 + ac);
        As[ac + 0][ar] = av.x; As[ac + 1][ar] = av.y;
        As[ac + 2][ar] = av.z; As[ac + 3][ar] = av.w;
        *reinterpret_cast<float4*>(&Bs[br][bc]) =
            *reinterpret_cast<const float4*>(Bm + (size_t)(k0 + br) * N + bc);
        __syncthreads();
        #pragma unroll
        for (int kk = 0; kk < 16; kk++) {
            float4 a4 = *reinterpret_cast<const float4*>(&As[kk][ty * 4]);
            float4 b4 = *reinterpret_cast<const float4*>(&Bs[kk][tx * 4]);
            float aa[4] = {a4.x, a4.y, a4.z, a4.w};
            float bb[4] = {b4.x, b4.y, b4.z, b4.w};
            #pragma unroll
            for (int i = 0; i < 4; i++)
                #pragma unroll
                for (int j = 0; j < 4; j++)
                    acc[i][j] = fmaf(aa[i], bb[j], acc[i][j]);
        }
        __syncthreads();
    }
    #pragma unroll
    for (int i = 0; i < 4; i++) {
        int row = m0 + ty * 4 + i;
        #pragma unroll
        for (int j = 0; j < 4; j++)
            part[((size_t)kp * M + row) * N + tx * 4 + j] = acc[i][j];
    }
}

// Reduce KS partials + tanh -> wl1
template <int KS>
__global__ __launch_bounds__(256) void splitk_reduce_tanh(const float* __restrict__ part,
                                                          float* __restrict__ outp,
                                                          int total, size_t stride) {
    int i = blockIdx.x * 256 + threadIdx.x;
    if (i >= total) return;
    float s = 0.f;
    #pragma unroll
    for (int kp = 0; kp < KS; kp++) s += part[kp * stride + i];
    outp[i] = tanhf(s);
}

// ---------------------------------------------------------------------------
// bf16 MFMA GEMM (small-N variant, register-staged): C = A[M,K] @ Bt[N,K]^T.
// BM=64, BN=128, BK=64. N-guarded. EPI: 0 none, 1 tanh.
// ---------------------------------------------------------------------------
template <int EPI, bool OBF16>
__global__ __launch_bounds__(256) void gemm_mfma(const __hip_bfloat16* __restrict__ A,
                                                 const __hip_bfloat16* __restrict__ Bt,
                                                 void* __restrict__ Cout,
                                                 int M, int N, int K) {
    __shared__ alignas(16) unsigned short As[64 * 64];
    __shared__ alignas(16) unsigned short Bs[128 * 64];
    int tid = threadIdx.x;
    int m0 = blockIdx.y * 64, n0 = blockIdx.x * 128;
    int wave = tid >> 6, lane = tid & 63;
    int wm = (wave & 1) * 32, wn = (wave >> 1) * 64;
    int l15 = lane & 15, l4 = lane >> 4;
    f32x4_t acc[2][4] = {};

    for (int k0 = 0; k0 < K; k0 += 64) {
        #pragma unroll
        for (int p = 0; p < 2; p++) {
            int cch = tid + p * 256;
            int row = cch >> 3, slot = cch & 7;
            int s2 = slot ^ (row & 7);
            *reinterpret_cast<us8_t*>(&As[row * 64 + s2 * 8]) =
                *reinterpret_cast<const us8_t*>(&A[(size_t)(m0 + row) * K + k0 + slot * 8]);
        }
        #pragma unroll
        for (int p = 0; p < 4; p++) {
            int cch = tid + p * 256;
            int row = cch >> 3, slot = cch & 7;
            int s2 = slot ^ (row & 7);
            int rowg = n0 + row; if (rowg > N - 1) rowg = N - 1;  // clamp
            *reinterpret_cast<us8_t*>(&Bs[row * 64 + s2 * 8]) =
                *reinterpret_cast<const us8_t*>(&Bt[(size_t)rowg * K + k0 + slot * 8]);
        }
        __syncthreads();
        #pragma unroll
        for (int kw = 0; kw < 2; kw++) {
            int slot = kw * 4 + l4;
            bf16x8_t af[2], bfr[4];
            #pragma unroll
            for (int f = 0; f < 2; f++) {
                int ar = wm + f * 16 + l15;
                af[f] = *reinterpret_cast<const bf16x8_t*>(&As[ar * 64 + (slot ^ (ar & 7)) * 8]);
            }
            #pragma unroll
            for (int f = 0; f < 4; f++) {
                int br = wn + f * 16 + l15;
                bfr[f] = *reinterpret_cast<const bf16x8_t*>(&Bs[br * 64 + (slot ^ (br & 7)) * 8]);
            }
            #pragma unroll
            for (int i = 0; i < 2; i++)
                #pragma unroll
                for (int j = 0; j < 4; j++)
                    acc[i][j] = __builtin_amdgcn_mfma_f32_16x16x32_bf16(af[i], bfr[j], acc[i][j], 0, 0, 0);
        }
        __syncthreads();
    }

    #pragma unroll
    for (int i = 0; i < 2; i++) {
        int rbase = m0 + wm + i * 16 + l4 * 4;
        #pragma unroll
        for (int j = 0; j < 4; j++) {
            int col = n0 + wn + j * 16 + l15;
            if (col < N) {
                #pragma unroll
                for (int q = 0; q < 4; q++) {
                    float v = acc[i][j][q];
                    if (EPI == 1) v = tanhf(v);
                    size_t o = (size_t)(rbase + q) * N + col;
                    if (OBF16) ((__hip_bfloat16*)Cout)[o] = __float2bfloat16(v);
                    else       ((float*)Cout)[o] = v;
                }
            }
        }
    }
}

// ---------------------------------------------------------------------------
// GROUPED bf16 MFMA GEMM, 128x128 tile: 4 projections (r,k,v,g) in ONE
// dispatch, grid (N/128, M/128, 4) = 1024 blocks (4/CU). BK=64, 32 KB LDS.
// global_load_lds staging; XOR-swizzle via pre-swizzled global source.
// 32 MFMA per K-step (2x the 64x128 tile's MFMA density).
// z<3: f32 out; z==3: silu + bf16 out.
// ---------------------------------------------------------------------------
__global__ __launch_bounds__(256) void gemm_qkvg(const __hip_bfloat16* __restrict__ A0,
                                                 const __hip_bfloat16* __restrict__ A1,
                                                 const __hip_bfloat16* __restrict__ A2,
                                                 const __hip_bfloat16* __restrict__ A3,
                                                 const __hip_bfloat16* __restrict__ B0,
                                                 const __hip_bfloat16* __restrict__ B1,
                                                 const __hip_bfloat16* __restrict__ B2,
                                                 const __hip_bfloat16* __restrict__ B3,
                                                 float* __restrict__ C0,
                                                 float* __restrict__ C1,
                                                 float* __restrict__ C2,
                                                 __hip_bfloat16* __restrict__ C3,
                                                 int M, int N, int K) {
    int g = blockIdx.z;
    const __hip_bfloat16* A  = (g == 0) ? A0 : (g == 1) ? A1 : (g == 2) ? A2 : A3;
    const __hip_bfloat16* Bt = (g == 0) ? B0 : (g == 1) ? B1 : (g == 2) ? B2 : B3;
    __shared__ alignas(16) unsigned short As[128 * 64];
    __shared__ alignas(16) unsigned short Bs[128 * 64];
    int tid = threadIdx.x;
    int m0 = blockIdx.y * 128, n0 = blockIdx.x * 128;
    int wave = tid >> 6, lane = tid & 63;
    int wm = (wave & 1) * 64, wn = (wave >> 1) * 64;
    int l15 = lane & 15, l4 = lane >> 4;
    int lrow = lane >> 3, ls2 = lane & 7;
    f32x4_t acc[4][4] = {};

    for (int k0 = 0; k0 < K; k0 += 64) {
        // A: 128 rows, wave w covers [w*32, w*32+32) in 4 calls of 8 rows.
        #pragma unroll
        for (int ci = 0; ci < 4; ci++) {
            int r0 = wave * 32 + ci * 8;
            int row = r0 + lrow;
            int gs = ls2 ^ (row & 7);       // inverse-swizzled global slot
            gload16(&A[(size_t)(m0 + row) * K + k0 + gs * 8], &As[r0 * 64]);
            gload16(&Bt[(size_t)(n0 + row) * K + k0 + gs * 8], &Bs[r0 * 64]);
        }
        __syncthreads();
        #pragma unroll
        for (int kw = 0; kw < 2; kw++) {
            int slot = kw * 4 + l4;
            bf16x8_t af[4], bfr[4];
            #pragma unroll
            for (int f = 0; f < 4; f++) {
                int ar = wm + f * 16 + l15;
                af[f] = *reinterpret_cast<const bf16x8_t*>(&As[ar * 64 + (slot ^ (ar & 7)) * 8]);
                int br = wn + f * 16 + l15;
                bfr[f] = *reinterpret_cast<const bf16x8_t*>(&Bs[br * 64 + (slot ^ (br & 7)) * 8]);
            }
            #pragma unroll
            for (int i = 0; i < 4; i++)
                #pragma unroll
                for (int j = 0; j < 4; j++)
                    acc[i][j] = __builtin_amdgcn_mfma_f32_16x16x32_bf16(af[i], bfr[j], acc[i][j], 0, 0, 0);
        }
        __syncthreads();
    }

    float* Cf = (g == 0) ? C0 : (g == 1) ? C1 : C2;
    #pragma unroll
    for (int i = 0; i < 4; i++) {
        int rbase = m0 + wm + i * 16 + l4 * 4;
        #pragma unroll
        for (int j = 0; j < 4; j++) {
            int col = n0 + wn + j * 16 + l15;
            #pragma unroll
            for (int q = 0; q < 4; q++) {
                float v = acc[i][j][q];
                size_t o = (size_t)(rbase + q) * N + col;
                if (g == 3) {
                    v = v / (1.f + expf(-v));
                    C3[o] = __float2bfloat16(v);
                } else {
                    Cf[o] = v;
                }
            }
        }
    }
}

// Wo projection (single, gl-staged, 64x128 tile -> 512 blocks)
template <int EPI, bool OBF16>
__global__ __launch_bounds__(256) void gemm_mfma_gl(const __hip_bfloat16* __restrict__ A,
                                                    const __hip_bfloat16* __restrict__ Bt,
                                                    void* __restrict__ Cout,
                                                    int M, int N, int K) {
    __shared__ alignas(16) unsigned short As[64 * 64];
    __shared__ alignas(16) unsigned short Bs[128 * 64];
    int tid = threadIdx.x;
    int m0 = blockIdx.y * 64, n0 = blockIdx.x * 128;
    int wave = tid >> 6, lane = tid & 63;
    int wm = (wave & 1) * 32, wn = (wave >> 1) * 64;
    int l15 = lane & 15, l4 = lane >> 4;
    int lrow = lane >> 3, ls2 = lane & 7;
    f32x4_t acc[2][4] = {};

    for (int k0 = 0; k0 < K; k0 += 64) {
        #pragma unroll
        for (int ci = 0; ci < 2; ci++) {
            int r0 = wave * 16 + ci * 8;
            int row = r0 + lrow;
            int gs = ls2 ^ (row & 7);
            gload16(&A[(size_t)(m0 + row) * K + k0 + gs * 8], &As[r0 * 64]);
        }
        #pragma unroll
        for (int ci = 0; ci < 4; ci++) {
            int r0 = wave * 32 + ci * 8;
            int row = r0 + lrow;
            int gs = ls2 ^ (row & 7);
            gload16(&Bt[(size_t)(n0 + row) * K + k0 + gs * 8], &Bs[r0 * 64]);
        }
        __syncthreads();
        #pragma unroll
        for (int kw = 0; kw < 2; kw++) {
            int slot = kw * 4 + l4;
            bf16x8_t af[2], bfr[4];
            #pragma unroll
            for (int f = 0; f < 2; f++) {
                int ar = wm + f * 16 + l15;
                af[f] = *reinterpret_cast<const bf16x8_t*>(&As[ar * 64 + (slot ^ (ar & 7)) * 8]);
            }
            #pragma unroll
            for (int f = 0; f < 4; f++) {
                int br = wn + f * 16 + l15;
                bfr[f] = *reinterpret_cast<const bf16x8_t*>(&Bs[br * 64 + (slot ^ (br & 7)) * 8]);
            }
            #pragma unroll
            for (int i = 0; i < 2; i++)
                #pragma unroll
                for (int j = 0; j < 4; j++)
                    acc[i][j] = __builtin_amdgcn_mfma_f32_16x16x32_bf16(af[i], bfr[j], acc[i][j], 0, 0, 0);
        }
        __syncthreads();
    }

    #pragma unroll
    for (int i = 0; i < 2; i++) {
        int rbase = m0 + wm + i * 16 + l4 * 4;
        #pragma unroll
        for (int j = 0; j < 4; j++) {
            int col = n0 + wn + j * 16 + l15;
            #pragma unroll
            for (int q = 0; q < 4; q++) {
                float v = acc[i][j][q];
                size_t o = (size_t)(rbase + q) * N + col;
                if (OBF16) ((__hip_bfloat16*)Cout)[o] = __float2bfloat16(v);
                else       ((float*)Cout)[o] = v;
            }
        }
    }
}

// ---------------------------------------------------------------------------
// 5 mix deltas fused with wx/kx/vx/rx/gx build.
// Block = 4 bt-rows x 1024 cols (4 cols/thread). float4 w2 loads amortized
// over 4 rows; mix160 via block-uniform s_load; vectorized stores.
// ---------------------------------------------------------------------------
__global__ __launch_bounds__(256) void deltas_mix(const float* __restrict__ x,
                                                  const float* __restrict__ mix160,
                                                  const float* __restrict__ w2,
                                                  const float* __restrict__ wmaa,
                                                  const float* __restrict__ kmaa,
                                                  const float* __restrict__ vmaa,
                                                  const float* __restrict__ rmaa,
                                                  const float* __restrict__ gmaa,
                                                  float* __restrict__ wx,
                                                  __hip_bfloat16* __restrict__ kxb,
                                                  __hip_bfloat16* __restrict__ vxb,
                                                  __hip_bfloat16* __restrict__ rxb,
                                                  __hip_bfloat16* __restrict__ gxb) {
    int tid = threadIdx.x;
    int c4 = tid * 4;
    int r0 = blockIdx.x * 4;
    const float* mrow = mix160 + (size_t)r0 * 160;   // block-uniform base
    float xv[4][4], sx[4][4];
    #pragma unroll
    for (int r = 0; r < 4; r++) {
        int row = r0 + r;
        int t = row & (Tn - 1);
        size_t idx = (size_t)row * Cn + c4;
        float4 xvv = *reinterpret_cast<const float4*>(x + idx);
        float4 xp = (t > 0) ? *reinterpret_cast<const float4*>(x + idx - Cn)
                            : make_float4(0.f, 0.f, 0.f, 0.f);
        xv[r][0] = xvv.x; xv[r][1] = xvv.y; xv[r][2] = xvv.z; xv[r][3] = xvv.w;
        sx[r][0] = xp.x - xvv.x; sx[r][1] = xp.y - xvv.y;
        sx[r][2] = xp.z - xvv.z; sx[r][3] = xp.w - xvv.w;
    }
    #pragma unroll
    for (int f = 0; f < 5; f++) {
        float acc[4][4] = {};
        for (int dd = 0; dd < 32; dd++) {
            float4 wv = *reinterpret_cast<const float4*>(w2 + (size_t)(f * 32 + dd) * Cn + c4);
            float wvv[4] = {wv.x, wv.y, wv.z, wv.w};
            #pragma unroll
            for (int r = 0; r < 4; r++) {
                float ms = mrow[r * 160 + f * 32 + dd];    // scalar (s_load)
                #pragma unroll
                for (int j = 0; j < 4; j++)
                    acc[r][j] = fmaf(ms, wvv[j], acc[r][j]);
            }
        }
        const float* maa = (f == 0) ? wmaa : (f == 1) ? kmaa : (f == 2) ? vmaa
                         : (f == 3) ? rmaa : gmaa;
        float4 mv4 = *reinterpret_cast<const float4*>(maa + c4);
        float mvv[4] = {mv4.x, mv4.y, mv4.z, mv4.w};
        #pragma unroll
        for (int r = 0; r < 4; r++) {
            size_t idx = (size_t)(r0 + r) * Cn + c4;
            float val[4];
            #pragma unroll
            for (int j = 0; j < 4; j++)
                val[j] = xv[r][j] + sx[r][j] * (mvv[j] + acc[r][j]);
            if (f == 0) {
                *reinterpret_cast<float4*>(wx + idx) =
                    make_float4(val[0], val[1], val[2], val[3]);
            } else {
                ushort4 o;
                o.x = f2bf_bits(val[0]); o.y = f2bf_bits(val[1]);
                o.z = f2bf_bits(val[2]); o.w = f2bf_bits(val[3]);
                __hip_bfloat16* dst = (f == 1) ? kxb : (f == 2) ? vxb : (f == 3) ? rxb : gxb;
                *reinterpret_cast<ushort4*>(dst + idx) = o;
            }
        }
    }
}

// ---------------------------------------------------------------------------
// Chunked WKV stage A (MFMA): per (b,h,chunk):
//   Wtot[ch] = exp(sum lw); Bc[k][v] = sum_tau kd[tau][k]*vs[tau][v]
// ---------------------------------------------------------------------------
__global__ __launch_bounds__(256) void chunk_summary(const float* __restrict__ kb,
                                                     const float* __restrict__ vb,
                                                     const float* __restrict__ lw,
                                                     float* __restrict__ Bc,
                                                     float* __restrict__ Wtot) {
    int bid = blockIdx.x;
    int c = bid & 15, h = (bid >> 4) & 15, b = bid >> 8;
    size_t gbase = ((size_t)(b * Tn + c * CL) * Hn + h) * 64;
    int tid = threadIdx.x;
    __shared__ float linc[64][68];
    __shared__ float wtp[4][64];
    __shared__ alignas(16) __hip_bfloat16 kdT[64][72];  // [ch][tau]
    __shared__ alignas(16) __hip_bfloat16 vsT[64][72];  // [v][tau]
    int wave = tid >> 6, lane = tid & 63;
    {
        float acc = 0.f;
        #pragma unroll
        for (int i = 0; i < 16; i++) {
            int t = wave * 16 + i;
            acc += lw[gbase + (size_t)t * 1024 + lane];
            linc[t][lane] = acc;
        }
        wtp[wave][lane] = acc;
    }
    __syncthreads();
    {
        float off = 0.f;
        for (int g = 0; g < wave; g++) off += wtp[g][lane];
        #pragma unroll
        for (int i = 0; i < 16; i++) linc[wave * 16 + i][lane] += off;
    }
    __syncthreads();
    int t4 = tid >> 2, c0 = (tid & 3) * 16;
    #pragma unroll
    for (int i = 0; i < 4; i++) {
        int ch = c0 + i * 4;
        size_t ga = gbase + (size_t)t4 * 1024 + ch;
        float4 k4 = *reinterpret_cast<const float4*>(kb + ga);
        float4 v4 = *reinterpret_cast<const float4*>(vb + ga);
        float kk[4] = {k4.x, k4.y, k4.z, k4.w};
        float vv[4] = {v4.x, v4.y, v4.z, v4.w};
        #pragma unroll
        for (int j = 0; j < 4; j++) {
            float li = linc[t4][ch + j];
            float lend = linc[63][ch + j];
            kdT[ch + j][t4] = __float2bfloat16(kk[j] * expf(lend - li));
            vsT[ch + j][t4] = __float2bfloat16(vv[j]);
        }
    }
    if (tid < 64) Wtot[(size_t)bid * 64 + tid] = expf(linc[63][tid]);
    __syncthreads();
    int l15 = lane & 15, l4q = lane >> 4;
    #pragma unroll
    for (int nt = 0; nt < 4; nt++) {
        f32x4_t acc = {};
        #pragma unroll
        for (int kt = 0; kt < 2; kt++) {
            bf16x8_t a = *reinterpret_cast<const bf16x8_t*>(&kdT[wave * 16 + l15][kt * 32 + l4q * 8]);
            bf16x8_t bb = *reinterpret_cast<const bf16x8_t*>(&vsT[nt * 16 + l15][kt * 32 + l4q * 8]);
            acc = __builtin_amdgcn_mfma_f32_16x16x32_bf16(a, bb, acc, 0, 0, 0);
        }
        #pragma unroll
        for (int q = 0; q < 4; q++) {
            int krow = wave * 16 + l4q * 4 + q;
            Bc[(size_t)bid * 4096 + (size_t)krow * 64 + nt * 16 + l15] = acc[q];
        }
    }
}

// ---------------------------------------------------------------------------
// Stage B: sequential scan over NC=16 chunk states; writes TRANSPOSED entry
// states SbufT[v][k].
// ---------------------------------------------------------------------------
__global__ __launch_bounds__(256) void chunk_scan(const float* __restrict__ Bc,
                                                  const float* __restrict__ Wtot,
                                                  float* __restrict__ SbufT) {
    int bid = blockIdx.x;
    int bh = bid >> 2, vg = bid & 3;
    int kk = threadIdx.x >> 2;
    int v = vg * 16 + (threadIdx.x & 3) * 4;
    float4 S = make_float4(0.f, 0.f, 0.f, 0.f);
    for (int c = 0; c < NC; c++) {
        size_t base = (size_t)(bh * NC + c) * 4096;
        SbufT[base + (size_t)(v + 0) * 64 + kk] = S.x;
        SbufT[base + (size_t)(v + 1) * 64 + kk] = S.y;
        SbufT[base + (size_t)(v + 2) * 64 + kk] = S.z;
        SbufT[base + (size_t)(v + 3) * 64 + kk] = S.w;
        float wt = Wtot[(size_t)(bh * NC + c) * 64 + kk];
        float4 b4 = *reinterpret_cast<const float4*>(Bc + base + (size_t)kk * 64 + v);
        S.x = fmaf(wt, S.x, b4.x);
        S.y = fmaf(wt, S.y, b4.y);
        S.z = fmaf(wt, S.z, b4.z);
        S.w = fmaf(wt, S.w, b4.w);
    }
}

// ---------------------------------------------------------------------------
// Stage C (MFMA): Y = mask(qs@ks^T, diag) @ V + qs @ Sc
// ---------------------------------------------------------------------------
__global__ __launch_bounds__(256) void chunk_out(const float* __restrict__ rb,
                                                 const float* __restrict__ kb,
                                                 const float* __restrict__ vb,
                                                 const float* __restrict__ lw,
                                                 const float* __restrict__ SbufT,
                                                 const float* __restrict__ tf,
                                                 float* __restrict__ y) {
    int bid = blockIdx.x;
    int c = bid & 15, h = (bid >> 4) & 15, b = bid >> 8;
    size_t gbase = ((size_t)(b * Tn + c * CL) * Hn + h) * 64;
    int tid = threadIdx.x;
    __shared__ alignas(16) __hip_bfloat16 qs[64][72];   // [t][ch]
    __shared__ alignas(16) __hip_bfloat16 ks[64][72];   // [tau][ch]
    __shared__ alignas(16) __hip_bfloat16 vsT[64][72];  // [v][tau]
    __shared__ alignas(16) __hip_bfloat16 scT[64][72];  // [v][ch]
    __shared__ alignas(16) float uni[64 * 68];          // linc, then asb
    __shared__ float wtp[4][64];
    __shared__ float diag[64];
    float (*linc)[68] = reinterpret_cast<float(*)[68]>(uni);
    __hip_bfloat16 (*asb)[72] = reinterpret_cast<__hip_bfloat16(*)[72]>(uni);
    int wave = tid >> 6, lane = tid & 63;
    {
        float acc = 0.f;
        #pragma unroll
        for (int i = 0; i < 16; i++) {
            int t = wave * 16 + i;
            acc += lw[gbase + (size_t)t * 1024 + lane];
            linc[t][lane] = acc;
        }
        wtp[wave][lane] = acc;
    }
    __syncthreads();
    {
        float off = 0.f;
        for (int g = 0; g < wave; g++) off += wtp[g][lane];
        #pragma unroll
        for (int i = 0; i < 16; i++) linc[wave * 16 + i][lane] += off;
    }
    __syncthreads();
    int t4 = tid >> 2, c0 = (tid & 3) * 16;
    float dpart = 0.f;
    #pragma unroll
    for (int i = 0; i < 4; i++) {
        int ch = c0 + i * 4;
        size_t ga = gbase + (size_t)t4 * 1024 + ch;
        float4 r4 = *reinterpret_cast<const float4*>(rb + ga);
        float4 k4 = *reinterpret_cast<const float4*>(kb + ga);
        float4 v4 = *reinterpret_cast<const float4*>(vb + ga);
        float4 l4v = *reinterpret_cast<const float4*>(lw + ga);
        float4 u4 = *reinterpret_cast<const float4*>(tf + h * 64 + ch);
        float4 s4 = *reinterpret_cast<const float4*>(SbufT + (size_t)bid * 4096 + (size_t)t4 * 64 + ch);
        float rr[4] = {r4.x, r4.y, r4.z, r4.w};
        float kkv[4] = {k4.x, k4.y, k4.z, k4.w};
        float vv[4] = {v4.x, v4.y, v4.z, v4.w};
        float lwv[4] = {l4v.x, l4v.y, l4v.z, l4v.w};
        float uu[4] = {u4.x, u4.y, u4.z, u4.w};
        float ss[4] = {s4.x, s4.y, s4.z, s4.w};
        #pragma unroll
        for (int j = 0; j < 4; j++) {
            float li = linc[t4][ch + j];
            qs[t4][ch + j] = __float2bfloat16(rr[j] * expf(li - lwv[j]));
            ks[t4][ch + j] = __float2bfloat16(kkv[j] * expf(-li));
            vsT[ch + j][t4] = __float2bfloat16(vv[j]);
            scT[t4][ch + j] = __float2bfloat16(ss[j]);   // row t4 = v
            dpart = fmaf(rr[j] * uu[j], kkv[j], dpart);
        }
    }
    dpart += __shfl_xor(dpart, 1);
    dpart += __shfl_xor(dpart, 2);
    if ((tid & 3) == 0) diag[t4] = dpart;
    __syncthreads();        // linc dead; asb may now overwrite uni
    int l15 = lane & 15, l4q = lane >> 4;
    #pragma unroll
    for (int nt = 0; nt < 4; nt++) {
        f32x4_t acc = {};
        if (nt <= wave) {
            #pragma unroll
            for (int kt = 0; kt < 2; kt++) {
                bf16x8_t a = *reinterpret_cast<const bf16x8_t*>(&qs[wave * 16 + l15][kt * 32 + l4q * 8]);
                bf16x8_t bb = *reinterpret_cast<const bf16x8_t*>(&ks[nt * 16 + l15][kt * 32 + l4q * 8]);
                acc = __builtin_amdgcn_mfma_f32_16x16x32_bf16(a, bb, acc, 0, 0, 0);
            }
        }
        #pragma unroll
        for (int q = 0; q < 4; q++) {
            int t = wave * 16 + l4q * 4 + q;
            int tau = nt * 16 + l15;
            float v = (tau < t) ? acc[q] : (tau == t ? diag[t] : 0.f);
            asb[t][tau] = __float2bfloat16(v);
        }
    }
    __syncthreads();
    #pragma unroll
    for (int nt = 0; nt < 4; nt++) {
        f32x4_t acc = {};
        int kmax = (wave >> 1) + 1;
        for (int kt = 0; kt < kmax; kt++) {
            bf16x8_t a = *reinterpret_cast<const bf16x8_t*>(&asb[wave * 16 + l15][kt * 32 + l4q * 8]);
            bf16x8_t bb = *reinterpret_cast<const bf16x8_t*>(&vsT[nt * 16 + l15][kt * 32 + l4q * 8]);
            acc = __builtin_amdgcn_mfma_f32_16x16x32_bf16(a, bb, acc, 0, 0, 0);
        }
        #pragma unroll
        for (int kt = 0; kt < 2; kt++) {
            bf16x8_t a = *reinterpret_cast<const bf16x8_t*>(&qs[wave * 16 + l15][kt * 32 + l4q * 8]);
            bf16x8_t bb = *reinterpret_cast<const bf16x8_t*>(&scT[nt * 16 + l15][kt * 32 + l4q * 8]);
            acc = __builtin_amdgcn_mfma_f32_16x16x32_bf16(a, bb, acc, 0, 0, 0);
        }
        #pragma unroll
        for (int q = 0; q < 4; q++) {
            int t = wave * 16 + l4q * 4 + q;
            y[gbase + (size_t)t * 1024 + nt * 16 + l15] = acc[q];
        }
    }
}

// ---------------------------------------------------------------------------
// GroupNorm per (bt,h) over 64 channels (after /8), *ln_w + ln_b, then *g.
// ---------------------------------------------------------------------------
__global__ __launch_bounds__(256) void gn_mul(const float* __restrict__ y,
                                              const __hip_bfloat16* __restrict__ g,
                                              const float* __restrict__ lnw,
                                              const float* __restrict__ lnb,
                                              __hip_bfloat16* __restrict__ fin) {
    int tid = threadIdx.x;
    int lane = tid & 63;
    int wv = tid >> 6;
    int grp = blockIdx.x * 4 + wv;    // bt*16 + h
    int h = grp & 15;
    size_t idx = (size_t)grp * 64 + lane;
    float val = y[idx] * 0.125f;
    float sum = val, sq = val * val;
    #pragma unroll
    for (int off = 32; off > 0; off >>= 1) {
        sum += __shfl_xor(sum, off, 64);
        sq  += __shfl_xor(sq,  off, 64);
    }
    float mu = sum * (1.f / 64.f);
    float var = sq * (1.f / 64.f) - mu * mu;
    float rs = rsqrtf(var + 1e-5f);
    float o = (val - mu) * rs * lnw[h * 64 + lane] + lnb[h * 64 + lane];
    fin[idx] = __float2bfloat16(o * __bfloat162float(g[idx]));
}

// ---------------------------------------------------------------------------
extern "C" void kernel_launch(void* const* d_in, const int* in_sizes, int n_in,
                              void* d_out, int out_size, void* d_ws, size_t ws_size,
                              hipStream_t stream) {
    (void)in_sizes; (void)n_in; (void)out_size; (void)ws_size;
    const float* x      = (const float*)d_in[0];
    const float* x_maa  = (const float*)d_in[1];
    const float* w_maa  = (const float*)d_in[2];
    const float* k_maa  = (const float*)d_in[3];
    const float* v_maa  = (const float*)d_in[4];
    const float* r_maa  = (const float*)d_in[5];
    const float* g_maa  = (const float*)d_in[6];
    const float* tm_w1  = (const float*)d_in[7];
    const float* tm_w2  = (const float*)d_in[8];
    const float* td_w1  = (const float*)d_in[9];
    const float* td_w2  = (const float*)d_in[10];
    const float* t_dec  = (const float*)d_in[11];
    const float* t_first= (const float*)d_in[12];
    const float* Wr     = (const float*)d_in[13];
    const float* Wk     = (const float*)d_in[14];
    const float* Wv     = (const float*)d_in[15];
    const float* Wg     = (const float*)d_in[16];
    const float* Wo     = (const float*)d_in[17];
    const float* ln_w   = (const float*)d_in[18];
    const float* ln_b   = (const float*)d_in[19];
    float* out = (float*)d_out;

    // Byte allocator, 256B aligned
    char* ws = (char*)d_ws;
    size_t off = 0;
    auto alloc = [&](size_t bytes) -> void* {
        void* p = ws + off;
        off = (off + bytes + 255) & ~(size_t)255;
        return p;
    };
    __hip_bfloat16* mixin = (__hip_bfloat16*)alloc(BTC * 4);  // bf16 used; slot also aliases rb (f32)
    float* mix160 = (float*)alloc((size_t)BT * 160 * 4);
    float* wxr    = (float*)alloc(BTC * 4);            // wx -> BcB -> ybuf
    __hip_bfloat16* kxb = (__hip_bfloat16*)alloc(BTC * 2);  // alias: fin
    __hip_bfloat16* vxb = (__hip_bfloat16*)alloc(BTC * 2);
    __hip_bfloat16* rxb = (__hip_bfloat16*)alloc(BTC * 2);  // rxb+gxb -> SbufT (16MB)
    __hip_bfloat16* gxb = (__hip_bfloat16*)alloc(BTC * 2);
    float* kb  = (float*)alloc(BTC * 4);
    float* vb  = (float*)alloc(BTC * 4);
    __hip_bfloat16* gb = (__hip_bfloat16*)alloc(BTC * 2);
    float* wl1 = (float*)alloc((size_t)BT * 64 * 4);   // alias: WtB
    float* lwb = (float*)alloc(BTC * 4);
    __hip_bfloat16* WrT = (__hip_bfloat16*)alloc((size_t)Cn * Cn * 2);
    __hip_bfloat16* WkT = (__hip_bfloat16*)alloc((size_t)Cn * Cn * 2);
    __hip_bfloat16* WvT = (__hip_bfloat16*)alloc((size_t)Cn * Cn * 2);
    __hip_bfloat16* WgT = (__hip_bfloat16*)alloc((size_t)Cn * Cn * 2);
    __hip_bfloat16* WoT = (__hip_bfloat16*)alloc((size_t)Cn * Cn * 2);
    __hip_bfloat16* tmw1T = (__hip_bfloat16*)alloc((size_t)160 * Cn * 2);
    float* skpart = (float*)alloc((size_t)8 * BT * 64 * 4);   // split-K partials (8MB)
    // Aliases (stream-ordered; producers complete before reuse):
    float* rb    = (float*)mixin;  // r projection (mixin dead after LoRA1)
    float* BcB   = wxr;            // chunk contributions (wx dead after splitk)
    float* ybuf  = wxr;            // recurrence out (BcB dead after chunk_scan)
    float* WtB   = wl1;            // chunk decay totals (wl1 dead after decay GEMM)
    float* SbufT = (float*)rxb;    // entry states (transposed), spans rxb+gxb
    __hip_bfloat16* fin = kxb;     // gn output (kxb dead after k projection)

    dim3 blk(256);
    // weight transpose+convert (one dispatch for the 5 square weights)
    transp5<<<dim3(32, 32, 5), blk, 0, stream>>>(Wr, Wk, Wv, Wg, Wo,
                                                 WrT, WkT, WvT, WgT, WoT);
    transp_bf16<<<dim3(5, 32), blk, 0, stream>>>(tm_w1, tmw1T, Cn, 160);
    // token-mix LoRA (MFMA, N=160 small-N variant)
    prep_mixin<<<dim3((unsigned)(BTC / 1024)), blk, 0, stream>>>(x, x_maa, mixin);
    gemm_mfma<1, false><<<dim3(2, 64), blk, 0, stream>>>(mixin, tmw1T, mix160, BT, 160, Cn);
    deltas_mix<<<dim3(BT / 4), blk, 0, stream>>>(x, mix160, tm_w2,
                                                 w_maa, k_maa, v_maa, r_maa, g_maa,
                                                 wxr, kxb, vxb, rxb, gxb);
    // projections: ONE grouped dispatch (r,k,v,g), 128x128 tile, 1024 blocks
    gemm_qkvg<<<dim3(8, 32, 4), blk, 0, stream>>>(rxb, kxb, vxb, gxb,
                                                  WrT, WkT, WvT, WgT,
                                                  rb, kb, vb, gb, BT, Cn, Cn);
    // decay LoRA1 (f32 split-K, 512 blocks) + fused reduce/tanh
    gemm_f32_splitk<8><<<dim3(8, 64), blk, 0, stream>>>(wxr, td_w1, skpart, BT, 64, Cn);
    splitk_reduce_tanh<8><<<dim3(BT * 64 / 256), blk, 0, stream>>>(skpart, wl1, BT * 64,
                                                                   (size_t)BT * 64);
    // decay GEMM2 (f32, precision-sensitive)
    gemm_f32<3><<<dim3(16, 64), blk, 0, stream>>>(wl1, td_w2, lwb, BT, Cn, 64, t_dec);
    // chunked scan (MFMA)
    chunk_summary<<<dim3(Bn * Hn * NC), blk, 0, stream>>>(kb, vb, lwb, BcB, WtB);
    chunk_scan<<<dim3(Bn * Hn * 4), blk, 0, stream>>>(BcB, WtB, SbufT);
    chunk_out<<<dim3(Bn * Hn * NC), blk, 0, stream>>>(rb, kb, vb, lwb, SbufT, t_first, ybuf);
    // epilogue
    gn_mul<<<dim3(BT * Hn / 4), blk, 0, stream>>>(ybuf, gb, ln_w, ln_b, fin);
    gemm_mfma_gl<0, false><<<dim3(8, 64), blk, 0, stream>>>(fin, WoT, out, BT, Cn, Cn);
}

// Round 11
// 222.727 us; speedup vs baseline: 1.1486x; 1.1486x over previous
//
#include <hip/hip_runtime.h>
#include <hip/hip_bf16.h>
#include <math.h>
#include <stdint.h>

// Problem constants
constexpr int Bn = 4, Tn = 1024, Cn = 1024, Hn = 16;
constexpr int BT = Bn * Tn;                 // 4096
constexpr long long BTC = (long long)BT * Cn;  // 4M elements
constexpr int CL = 64;                      // chunk length
constexpr int NC = Tn / CL;                 // 16 chunks

typedef __bf16 bf16x8_t __attribute__((ext_vector_type(8)));
typedef float f32x4_t __attribute__((ext_vector_type(4)));
typedef unsigned short us8_t __attribute__((ext_vector_type(8)));

__device__ __forceinline__ unsigned short f2bf_bits(float v) {
    __hip_bfloat16 h = __float2bfloat16(v);
    return *reinterpret_cast<unsigned short*>(&h);
}
__device__ __forceinline__ float bfbits2f(unsigned short u) {
    unsigned int x = (unsigned int)u << 16;
    return __uint_as_float(x);
}

// Direct global->LDS 16B/lane (wave-uniform LDS base + lane*16). CK-style casts.
__device__ __forceinline__ void gload16(const void* g, void* l) {
    auto const* gp = reinterpret_cast<const unsigned int __attribute__((address_space(1)))*>(
        reinterpret_cast<uintptr_t>(g));
    auto* lp = reinterpret_cast<unsigned int __attribute__((address_space(3)))*>(
        reinterpret_cast<uintptr_t>(l));
    __builtin_amdgcn_global_load_lds(gp, lp, 16, 0, 0);
}

// ---------------------------------------------------------------------------
// mix input for the token-mix LoRA (x4 vectorized)
// ---------------------------------------------------------------------------
__global__ __launch_bounds__(256) void prep_mixin(const float* __restrict__ x,
                                                  const float* __restrict__ x_maa,
                                                  __hip_bfloat16* __restrict__ out) {
    long long q = (long long)blockIdx.x * 256 + threadIdx.x;   // quad index
    if (q * 4 >= BTC) return;
    long long idx = q * 4;
    int c = (int)(idx & (Cn - 1));
    long long bt = idx >> 10;
    int t = (int)(bt & (Tn - 1));
    float4 xv = *reinterpret_cast<const float4*>(x + idx);
    float4 xp = (t > 0) ? *reinterpret_cast<const float4*>(x + idx - Cn)
                        : make_float4(0.f, 0.f, 0.f, 0.f);
    float4 ma = *reinterpret_cast<const float4*>(x_maa + c);
    ushort4 o;
    o.x = f2bf_bits(xv.x + (xp.x - xv.x) * ma.x);
    o.y = f2bf_bits(xv.y + (xp.y - xv.y) * ma.y);
    o.z = f2bf_bits(xv.z + (xp.z - xv.z) * ma.z);
    o.w = f2bf_bits(xv.w + (xp.w - xv.w) * ma.w);
    *reinterpret_cast<ushort4*>(out + idx) = o;
}

// ---------------------------------------------------------------------------
// Transpose + convert, 5 square weights in one dispatch (z selects matrix).
// ---------------------------------------------------------------------------
__global__ __launch_bounds__(256) void transp5(const float* __restrict__ W0,
                                               const float* __restrict__ W1,
                                               const float* __restrict__ W2,
                                               const float* __restrict__ W3,
                                               const float* __restrict__ W4,
                                               __hip_bfloat16* __restrict__ T0,
                                               __hip_bfloat16* __restrict__ T1,
                                               __hip_bfloat16* __restrict__ T2,
                                               __hip_bfloat16* __restrict__ T3,
                                               __hip_bfloat16* __restrict__ T4) {
    int z = blockIdx.z;
    const float* W = (z == 0) ? W0 : (z == 1) ? W1 : (z == 2) ? W2 : (z == 3) ? W3 : W4;
    __hip_bfloat16* Wt = (z == 0) ? T0 : (z == 1) ? T1 : (z == 2) ? T2 : (z == 3) ? T3 : T4;
    __shared__ float tile[32][33];
    int c0 = blockIdx.x * 32, r0 = blockIdx.y * 32;
    int tx = threadIdx.x & 31, ty = threadIdx.x >> 5;
    #pragma unroll
    for (int i = 0; i < 4; i++)
        tile[ty + 8 * i][tx] = W[(size_t)(r0 + ty + 8 * i) * Cn + c0 + tx];
    __syncthreads();
    #pragma unroll
    for (int i = 0; i < 4; i++)
        Wt[(size_t)(c0 + ty + 8 * i) * Cn + r0 + tx] = __float2bfloat16(tile[tx][ty + 8 * i]);
}

// Generic single transpose (tm_w1: [Cn,160] -> [160,Cn])
__global__ __launch_bounds__(256) void transp_bf16(const float* __restrict__ W,
                                                   __hip_bfloat16* __restrict__ Wt,
                                                   int R, int Cc) {
    __shared__ float tile[32][33];
    int c0 = blockIdx.x * 32, r0 = blockIdx.y * 32;
    int tx = threadIdx.x & 31, ty = threadIdx.x >> 5;
    #pragma unroll
    for (int i = 0; i < 4; i++)
        tile[ty + 8 * i][tx] = W[(size_t)(r0 + ty + 8 * i) * Cc + c0 + tx];
    __syncthreads();
    #pragma unroll
    for (int i = 0; i < 4; i++)
        Wt[(size_t)(c0 + ty + 8 * i) * R + r0 + tx] = __float2bfloat16(tile[tx][ty + 8 * i]);
}

// ---------------------------------------------------------------------------
// f32 tiled GEMM (decay LoRA GEMM2, precision-sensitive): C = A[M,K]@B[K,N].
// EPI: 3 logdecay (-exp(extra[col]+acc))
// ---------------------------------------------------------------------------
template <int EPI>
__global__ __launch_bounds__(256) void gemm_f32(const float* __restrict__ A,
                                                const float* __restrict__ Bm,
                                                float* __restrict__ C,
                                                int M, int N, int K,
                                                const float* __restrict__ extra) {
    __shared__ float As[16][64];
    __shared__ float Bs[16][64];
    int tid = threadIdx.x;
    int m0 = blockIdx.y * 64, n0 = blockIdx.x * 64;
    int tx = tid & 15, ty = tid >> 4;
    int ar = tid >> 2, ac = (tid & 3) * 4;
    int br = tid >> 4, bc = (tid & 15) * 4;
    float acc[4][4] = {};

    for (int k0 = 0; k0 < K; k0 += 16) {
        const float* ap = A + (size_t)(m0 + ar) * K + k0 + ac;
        float4 av = *reinterpret_cast<const float4*>(ap);
        As[ac + 0][ar] = av.x; As[ac + 1][ar] = av.y;
        As[ac + 2][ar] = av.z; As[ac + 3][ar] = av.w;
        float4 bv = *reinterpret_cast<const float4*>(Bm + (size_t)(k0 + br) * N + n0 + bc);
        *reinterpret_cast<float4*>(&Bs[br][bc]) = bv;
        __syncthreads();
        #pragma unroll
        for (int kk = 0; kk < 16; kk++) {
            float4 a4 = *reinterpret_cast<const float4*>(&As[kk][ty * 4]);
            float4 b4 = *reinterpret_cast<const float4*>(&Bs[kk][tx * 4]);
            float aa[4] = {a4.x, a4.y, a4.z, a4.w};
            float bb[4] = {b4.x, b4.y, b4.z, b4.w};
            #pragma unroll
            for (int i = 0; i < 4; i++)
                #pragma unroll
                for (int j = 0; j < 4; j++)
                    acc[i][j] = fmaf(aa[i], bb[j], acc[i][j]);
        }
        __syncthreads();
    }

    #pragma unroll
    for (int i = 0; i < 4; i++) {
        int row = m0 + ty * 4 + i;
        #pragma unroll
        for (int j = 0; j < 4; j++) {
            int col = n0 + tx * 4 + j;
            float v = acc[i][j];
            if (EPI == 3) v = -expf(extra[col] + v);
            C[(size_t)row * N + col] = v;
        }
    }
}

// ---------------------------------------------------------------------------
// Split-K f32 GEMM for the decay LoRA1 ([4096,1024]@[1024,64], N==64).
// ---------------------------------------------------------------------------
template <int KS>
__global__ __launch_bounds__(256) void gemm_f32_splitk(const float* __restrict__ A,
                                                       const float* __restrict__ Bm,
                                                       float* __restrict__ part,
                                                       int M, int N, int K) {
    __shared__ float As[16][64];
    __shared__ float Bs[16][64];
    int tid = threadIdx.x;
    int kp = blockIdx.x;
    int m0 = blockIdx.y * 64;
    int kbeg = kp * (K / KS), kend = kbeg + K / KS;
    int tx = tid & 15, ty = tid >> 4;
    int ar = tid >> 2, ac = (tid & 3) * 4;
    int br = tid >> 4, bc = (tid & 15) * 4;
    float acc[4][4] = {};

    for (int k0 = kbeg; k0 < kend; k0 += 16) {
        float4 av = *reinterpret_cast<const float4*>(A + (size_t)(m0 + ar) * K + k0 + ac);
        As[ac + 0][ar] = av.x; As[ac + 1][ar] = av.y;
        As[ac + 2][ar] = av.z; As[ac + 3][ar] = av.w;
        *reinterpret_cast<float4*>(&Bs[br][bc]) =
            *reinterpret_cast<const float4*>(Bm + (size_t)(k0 + br) * N + bc);
        __syncthreads();
        #pragma unroll
        for (int kk = 0; kk < 16; kk++) {
            float4 a4 = *reinterpret_cast<const float4*>(&As[kk][ty * 4]);
            float4 b4 = *reinterpret_cast<const float4*>(&Bs[kk][tx * 4]);
            float aa[4] = {a4.x, a4.y, a4.z, a4.w};
            float bb[4] = {b4.x, b4.y, b4.z, b4.w};
            #pragma unroll
            for (int i = 0; i < 4; i++)
                #pragma unroll
                for (int j = 0; j < 4; j++)
                    acc[i][j] = fmaf(aa[i], bb[j], acc[i][j]);
        }
        __syncthreads();
    }
    #pragma unroll
    for (int i = 0; i < 4; i++) {
        int row = m0 + ty * 4 + i;
        #pragma unroll
        for (int j = 0; j < 4; j++)
            part[((size_t)kp * M + row) * N + tx * 4 + j] = acc[i][j];
    }
}

// Reduce KS partials + tanh
template <int KS>
__global__ __launch_bounds__(256) void splitk_reduce_tanh(const float* __restrict__ part,
                                                          float* __restrict__ outp,
                                                          int total, size_t stride) {
    int i = blockIdx.x * 256 + threadIdx.x;
    if (i >= total) return;
    float s = 0.f;
    #pragma unroll
    for (int kp = 0; kp < KS; kp++) s += part[kp * stride + i];
    outp[i] = tanhf(s);
}

// ---------------------------------------------------------------------------
// Split-K bf16 MFMA GEMM for token-mix LoRA1 ([4096,1024]@[1024,160]).
// BM=64, BN=128 (N-guarded), BK=64, K-range per z. Partials f32.
// Grid (ceil(N/128), M/64, KS) = (2, 64, 4) = 512 blocks.
// ---------------------------------------------------------------------------
template <int KS>
__global__ __launch_bounds__(256) void gemm_mfma_sk(const __hip_bfloat16* __restrict__ A,
                                                    const __hip_bfloat16* __restrict__ Bt,
                                                    float* __restrict__ part,
                                                    int M, int N, int K) {
    __shared__ alignas(16) unsigned short As[64 * 64];
    __shared__ alignas(16) unsigned short Bs[128 * 64];
    int tid = threadIdx.x;
    int m0 = blockIdx.y * 64, n0 = blockIdx.x * 128;
    int kp = blockIdx.z;
    int kbeg = kp * (K / KS), kend = kbeg + K / KS;
    int wave = tid >> 6, lane = tid & 63;
    int wm = (wave & 1) * 32, wn = (wave >> 1) * 64;
    int l15 = lane & 15, l4 = lane >> 4;
    f32x4_t acc[2][4] = {};

    for (int k0 = kbeg; k0 < kend; k0 += 64) {
        #pragma unroll
        for (int p = 0; p < 2; p++) {
            int cch = tid + p * 256;
            int row = cch >> 3, slot = cch & 7;
            int s2 = slot ^ (row & 7);
            *reinterpret_cast<us8_t*>(&As[row * 64 + s2 * 8]) =
                *reinterpret_cast<const us8_t*>(&A[(size_t)(m0 + row) * K + k0 + slot * 8]);
        }
        #pragma unroll
        for (int p = 0; p < 4; p++) {
            int cch = tid + p * 256;
            int row = cch >> 3, slot = cch & 7;
            int s2 = slot ^ (row & 7);
            int rowg = n0 + row; if (rowg > N - 1) rowg = N - 1;  // clamp
            *reinterpret_cast<us8_t*>(&Bs[row * 64 + s2 * 8]) =
                *reinterpret_cast<const us8_t*>(&Bt[(size_t)rowg * K + k0 + slot * 8]);
        }
        __syncthreads();
        #pragma unroll
        for (int kw = 0; kw < 2; kw++) {
            int slot = kw * 4 + l4;
            bf16x8_t af[2], bfr[4];
            #pragma unroll
            for (int f = 0; f < 2; f++) {
                int ar = wm + f * 16 + l15;
                af[f] = *reinterpret_cast<const bf16x8_t*>(&As[ar * 64 + (slot ^ (ar & 7)) * 8]);
            }
            #pragma unroll
            for (int f = 0; f < 4; f++) {
                int br = wn + f * 16 + l15;
                bfr[f] = *reinterpret_cast<const bf16x8_t*>(&Bs[br * 64 + (slot ^ (br & 7)) * 8]);
            }
            #pragma unroll
            for (int i = 0; i < 2; i++)
                #pragma unroll
                for (int j = 0; j < 4; j++)
                    acc[i][j] = __builtin_amdgcn_mfma_f32_16x16x32_bf16(af[i], bfr[j], acc[i][j], 0, 0, 0);
        }
        __syncthreads();
    }

    #pragma unroll
    for (int i = 0; i < 2; i++) {
        int rbase = m0 + wm + i * 16 + l4 * 4;
        #pragma unroll
        for (int j = 0; j < 4; j++) {
            int col = n0 + wn + j * 16 + l15;
            if (col < N) {
                #pragma unroll
                for (int q = 0; q < 4; q++)
                    part[((size_t)kp * M + rbase + q) * N + col] = acc[i][j][q];
            }
        }
    }
}

// ---------------------------------------------------------------------------
// GROUPED bf16 MFMA GEMM: 4 projections (r,k,v,g) in ONE dispatch.
// 64x128 tile, grid (8,64,4)=2048 blocks. global_load_lds staging.
// ALL outputs bf16 now; z==3 applies silu.
// ---------------------------------------------------------------------------
__global__ __launch_bounds__(256) void gemm_qkvg(const __hip_bfloat16* __restrict__ A0,
                                                 const __hip_bfloat16* __restrict__ A1,
                                                 const __hip_bfloat16* __restrict__ A2,
                                                 const __hip_bfloat16* __restrict__ A3,
                                                 const __hip_bfloat16* __restrict__ B0,
                                                 const __hip_bfloat16* __restrict__ B1,
                                                 const __hip_bfloat16* __restrict__ B2,
                                                 const __hip_bfloat16* __restrict__ B3,
                                                 __hip_bfloat16* __restrict__ C0,
                                                 __hip_bfloat16* __restrict__ C1,
                                                 __hip_bfloat16* __restrict__ C2,
                                                 __hip_bfloat16* __restrict__ C3,
                                                 int M, int N, int K) {
    int g = blockIdx.z;
    const __hip_bfloat16* A  = (g == 0) ? A0 : (g == 1) ? A1 : (g == 2) ? A2 : A3;
    const __hip_bfloat16* Bt = (g == 0) ? B0 : (g == 1) ? B1 : (g == 2) ? B2 : B3;
    __hip_bfloat16* Co = (g == 0) ? C0 : (g == 1) ? C1 : (g == 2) ? C2 : C3;
    __shared__ alignas(16) unsigned short As[64 * 64];
    __shared__ alignas(16) unsigned short Bs[128 * 64];
    int tid = threadIdx.x;
    int m0 = blockIdx.y * 64, n0 = blockIdx.x * 128;
    int wave = tid >> 6, lane = tid & 63;
    int wm = (wave & 1) * 32, wn = (wave >> 1) * 64;
    int l15 = lane & 15, l4 = lane >> 4;
    int lrow = lane >> 3, ls2 = lane & 7;
    f32x4_t acc[2][4] = {};

    for (int k0 = 0; k0 < K; k0 += 64) {
        #pragma unroll
        for (int ci = 0; ci < 2; ci++) {
            int r0 = wave * 16 + ci * 8;
            int row = r0 + lrow;
            int gs = ls2 ^ (row & 7);
            gload16(&A[(size_t)(m0 + row) * K + k0 + gs * 8], &As[r0 * 64]);
        }
        #pragma unroll
        for (int ci = 0; ci < 4; ci++) {
            int r0 = wave * 32 + ci * 8;
            int row = r0 + lrow;
            int gs = ls2 ^ (row & 7);
            gload16(&Bt[(size_t)(n0 + row) * K + k0 + gs * 8], &Bs[r0 * 64]);
        }
        __syncthreads();
        #pragma unroll
        for (int kw = 0; kw < 2; kw++) {
            int slot = kw * 4 + l4;
            bf16x8_t af[2], bfr[4];
            #pragma unroll
            for (int f = 0; f < 2; f++) {
                int ar = wm + f * 16 + l15;
                af[f] = *reinterpret_cast<const bf16x8_t*>(&As[ar * 64 + (slot ^ (ar & 7)) * 8]);
            }
            #pragma unroll
            for (int f = 0; f < 4; f++) {
                int br = wn + f * 16 + l15;
                bfr[f] = *reinterpret_cast<const bf16x8_t*>(&Bs[br * 64 + (slot ^ (br & 7)) * 8]);
            }
            #pragma unroll
            for (int i = 0; i < 2; i++)
                #pragma unroll
                for (int j = 0; j < 4; j++)
                    acc[i][j] = __builtin_amdgcn_mfma_f32_16x16x32_bf16(af[i], bfr[j], acc[i][j], 0, 0, 0);
        }
        __syncthreads();
    }

    #pragma unroll
    for (int i = 0; i < 2; i++) {
        int rbase = m0 + wm + i * 16 + l4 * 4;
        #pragma unroll
        for (int j = 0; j < 4; j++) {
            int col = n0 + wn + j * 16 + l15;
            #pragma unroll
            for (int q = 0; q < 4; q++) {
                float v = acc[i][j][q];
                if (g == 3) v = v / (1.f + expf(-v));
                Co[(size_t)(rbase + q) * N + col] = __float2bfloat16(v);
            }
        }
    }
}

// Wo projection (single, gl-staged, 64x128 tile -> 512 blocks), f32 out
__global__ __launch_bounds__(256) void gemm_mfma_gl(const __hip_bfloat16* __restrict__ A,
                                                    const __hip_bfloat16* __restrict__ Bt,
                                                    float* __restrict__ Cout,
                                                    int M, int N, int K) {
    __shared__ alignas(16) unsigned short As[64 * 64];
    __shared__ alignas(16) unsigned short Bs[128 * 64];
    int tid = threadIdx.x;
    int m0 = blockIdx.y * 64, n0 = blockIdx.x * 128;
    int wave = tid >> 6, lane = tid & 63;
    int wm = (wave & 1) * 32, wn = (wave >> 1) * 64;
    int l15 = lane & 15, l4 = lane >> 4;
    int lrow = lane >> 3, ls2 = lane & 7;
    f32x4_t acc[2][4] = {};

    for (int k0 = 0; k0 < K; k0 += 64) {
        #pragma unroll
        for (int ci = 0; ci < 2; ci++) {
            int r0 = wave * 16 + ci * 8;
            int row = r0 + lrow;
            int gs = ls2 ^ (row & 7);
            gload16(&A[(size_t)(m0 + row) * K + k0 + gs * 8], &As[r0 * 64]);
        }
        #pragma unroll
        for (int ci = 0; ci < 4; ci++) {
            int r0 = wave * 32 + ci * 8;
            int row = r0 + lrow;
            int gs = ls2 ^ (row & 7);
            gload16(&Bt[(size_t)(n0 + row) * K + k0 + gs * 8], &Bs[r0 * 64]);
        }
        __syncthreads();
        #pragma unroll
        for (int kw = 0; kw < 2; kw++) {
            int slot = kw * 4 + l4;
            bf16x8_t af[2], bfr[4];
            #pragma unroll
            for (int f = 0; f < 2; f++) {
                int ar = wm + f * 16 + l15;
                af[f] = *reinterpret_cast<const bf16x8_t*>(&As[ar * 64 + (slot ^ (ar & 7)) * 8]);
            }
            #pragma unroll
            for (int f = 0; f < 4; f++) {
                int br = wn + f * 16 + l15;
                bfr[f] = *reinterpret_cast<const bf16x8_t*>(&Bs[br * 64 + (slot ^ (br & 7)) * 8]);
            }
            #pragma unroll
            for (int i = 0; i < 2; i++)
                #pragma unroll
                for (int j = 0; j < 4; j++)
                    acc[i][j] = __builtin_amdgcn_mfma_f32_16x16x32_bf16(af[i], bfr[j], acc[i][j], 0, 0, 0);
        }
        __syncthreads();
    }

    #pragma unroll
    for (int i = 0; i < 2; i++) {
        int rbase = m0 + wm + i * 16 + l4 * 4;
        #pragma unroll
        for (int j = 0; j < 4; j++) {
            int col = n0 + wn + j * 16 + l15;
            #pragma unroll
            for (int q = 0; q < 4; q++)
                Cout[(size_t)(rbase + q) * N + col] = acc[i][j][q];
        }
    }
}

// ---------------------------------------------------------------------------
// 5 mix deltas fused with wx/kx/vx/rx/gx build.
// Block = 4 bt-rows x 1024 cols (4 cols/thread). float4 w2 loads amortized
// over 4 rows; mix160 via block-uniform s_load; vectorized stores.
// ---------------------------------------------------------------------------
__global__ __launch_bounds__(256) void deltas_mix(const float* __restrict__ x,
                                                  const float* __restrict__ mix160,
                                                  const float* __restrict__ w2,
                                                  const float* __restrict__ wmaa,
                                                  const float* __restrict__ kmaa,
                                                  const float* __restrict__ vmaa,
                                                  const float* __restrict__ rmaa,
                                                  const float* __restrict__ gmaa,
                                                  float* __restrict__ wx,
                                                  __hip_bfloat16* __restrict__ kxb,
                                                  __hip_bfloat16* __restrict__ vxb,
                                                  __hip_bfloat16* __restrict__ rxb,
                                                  __hip_bfloat16* __restrict__ gxb) {
    int tid = threadIdx.x;
    int c4 = tid * 4;
    int r0 = blockIdx.x * 4;
    const float* mrow = mix160 + (size_t)r0 * 160;   // block-uniform base
    float xv[4][4], sx[4][4];
    #pragma unroll
    for (int r = 0; r < 4; r++) {
        int row = r0 + r;
        int t = row & (Tn - 1);
        size_t idx = (size_t)row * Cn + c4;
        float4 xvv = *reinterpret_cast<const float4*>(x + idx);
        float4 xp = (t > 0) ? *reinterpret_cast<const float4*>(x + idx - Cn)
                            : make_float4(0.f, 0.f, 0.f, 0.f);
        xv[r][0] = xvv.x; xv[r][1] = xvv.y; xv[r][2] = xvv.z; xv[r][3] = xvv.w;
        sx[r][0] = xp.x - xvv.x; sx[r][1] = xp.y - xvv.y;
        sx[r][2] = xp.z - xvv.z; sx[r][3] = xp.w - xvv.w;
    }
    #pragma unroll
    for (int f = 0; f < 5; f++) {
        float acc[4][4] = {};
        for (int dd = 0; dd < 32; dd++) {
            float4 wv = *reinterpret_cast<const float4*>(w2 + (size_t)(f * 32 + dd) * Cn + c4);
            float wvv[4] = {wv.x, wv.y, wv.z, wv.w};
            #pragma unroll
            for (int r = 0; r < 4; r++) {
                float ms = mrow[r * 160 + f * 32 + dd];    // scalar (s_load)
                #pragma unroll
                for (int j = 0; j < 4; j++)
                    acc[r][j] = fmaf(ms, wvv[j], acc[r][j]);
            }
        }
        const float* maa = (f == 0) ? wmaa : (f == 1) ? kmaa : (f == 2) ? vmaa
                         : (f == 3) ? rmaa : gmaa;
        float4 mv4 = *reinterpret_cast<const float4*>(maa + c4);
        float mvv[4] = {mv4.x, mv4.y, mv4.z, mv4.w};
        #pragma unroll
        for (int r = 0; r < 4; r++) {
            size_t idx = (size_t)(r0 + r) * Cn + c4;
            float val[4];
            #pragma unroll
            for (int j = 0; j < 4; j++)
                val[j] = xv[r][j] + sx[r][j] * (mvv[j] + acc[r][j]);
            if (f == 0) {
                *reinterpret_cast<float4*>(wx + idx) =
                    make_float4(val[0], val[1], val[2], val[3]);
            } else {
                ushort4 o;
                o.x = f2bf_bits(val[0]); o.y = f2bf_bits(val[1]);
                o.z = f2bf_bits(val[2]); o.w = f2bf_bits(val[3]);
                __hip_bfloat16* dst = (f == 1) ? kxb : (f == 2) ? vxb : (f == 3) ? rxb : gxb;
                *reinterpret_cast<ushort4*>(dst + idx) = o;
            }
        }
    }
}

// ---------------------------------------------------------------------------
// Chunked WKV stage A (MFMA): per (b,h,chunk). k/v inputs now bf16.
//   Wtot[ch] = exp(sum lw); Bc[k][v] = sum_tau kd[tau][k]*vs[tau][v]
// ---------------------------------------------------------------------------
__global__ __launch_bounds__(256) void chunk_summary(const __hip_bfloat16* __restrict__ kb,
                                                     const __hip_bfloat16* __restrict__ vb,
                                                     const float* __restrict__ lw,
                                                     float* __restrict__ Bc,
                                                     float* __restrict__ Wtot) {
    int bid = blockIdx.x;
    int c = bid & 15, h = (bid >> 4) & 15, b = bid >> 8;
    size_t gbase = ((size_t)(b * Tn + c * CL) * Hn + h) * 64;
    int tid = threadIdx.x;
    __shared__ float linc[64][68];
    __shared__ float wtp[4][64];
    __shared__ alignas(16) __hip_bfloat16 kdT[64][72];  // [ch][tau]
    __shared__ alignas(16) __hip_bfloat16 vsT[64][72];  // [v][tau]
    int wave = tid >> 6, lane = tid & 63;
    {
        float acc = 0.f;
        #pragma unroll
        for (int i = 0; i < 16; i++) {
            int t = wave * 16 + i;
            acc += lw[gbase + (size_t)t * 1024 + lane];
            linc[t][lane] = acc;
        }
        wtp[wave][lane] = acc;
    }
    __syncthreads();
    {
        float off = 0.f;
        for (int g = 0; g < wave; g++) off += wtp[g][lane];
        #pragma unroll
        for (int i = 0; i < 16; i++) linc[wave * 16 + i][lane] += off;
    }
    __syncthreads();
    int t4 = tid >> 2, c0 = (tid & 3) * 16;
    #pragma unroll
    for (int i = 0; i < 4; i++) {
        int ch = c0 + i * 4;
        size_t ga = gbase + (size_t)t4 * 1024 + ch;
        ushort4 ku = *reinterpret_cast<const ushort4*>(kb + ga);
        ushort4 vu = *reinterpret_cast<const ushort4*>(vb + ga);
        float kk[4] = {bfbits2f(ku.x), bfbits2f(ku.y), bfbits2f(ku.z), bfbits2f(ku.w)};
        float vv[4] = {bfbits2f(vu.x), bfbits2f(vu.y), bfbits2f(vu.z), bfbits2f(vu.w)};
        #pragma unroll
        for (int j = 0; j < 4; j++) {
            float li = linc[t4][ch + j];
            float lend = linc[63][ch + j];
            kdT[ch + j][t4] = __float2bfloat16(kk[j] * expf(lend - li));
            vsT[ch + j][t4] = __float2bfloat16(vv[j]);
        }
    }
    if (tid < 64) Wtot[(size_t)bid * 64 + tid] = expf(linc[63][tid]);
    __syncthreads();
    int l15 = lane & 15, l4q = lane >> 4;
    #pragma unroll
    for (int nt = 0; nt < 4; nt++) {
        f32x4_t acc = {};
        #pragma unroll
        for (int kt = 0; kt < 2; kt++) {
            bf16x8_t a = *reinterpret_cast<const bf16x8_t*>(&kdT[wave * 16 + l15][kt * 32 + l4q * 8]);
            bf16x8_t bb = *reinterpret_cast<const bf16x8_t*>(&vsT[nt * 16 + l15][kt * 32 + l4q * 8]);
            acc = __builtin_amdgcn_mfma_f32_16x16x32_bf16(a, bb, acc, 0, 0, 0);
        }
        #pragma unroll
        for (int q = 0; q < 4; q++) {
            int krow = wave * 16 + l4q * 4 + q;
            Bc[(size_t)bid * 4096 + (size_t)krow * 64 + nt * 16 + l15] = acc[q];
        }
    }
}

// ---------------------------------------------------------------------------
// Stage B: sequential scan over NC=16 chunk states; TRANSPOSED entry states.
// ---------------------------------------------------------------------------
__global__ __launch_bounds__(256) void chunk_scan(const float* __restrict__ Bc,
                                                  const float* __restrict__ Wtot,
                                                  float* __restrict__ SbufT) {
    int bid = blockIdx.x;
    int bh = bid >> 2, vg = bid & 3;
    int kk = threadIdx.x >> 2;
    int v = vg * 16 + (threadIdx.x & 3) * 4;
    float4 S = make_float4(0.f, 0.f, 0.f, 0.f);
    for (int c = 0; c < NC; c++) {
        size_t base = (size_t)(bh * NC + c) * 4096;
        SbufT[base + (size_t)(v + 0) * 64 + kk] = S.x;
        SbufT[base + (size_t)(v + 1) * 64 + kk] = S.y;
        SbufT[base + (size_t)(v + 2) * 64 + kk] = S.z;
        SbufT[base + (size_t)(v + 3) * 64 + kk] = S.w;
        float wt = Wtot[(size_t)(bh * NC + c) * 64 + kk];
        float4 b4 = *reinterpret_cast<const float4*>(Bc + base + (size_t)kk * 64 + v);
        S.x = fmaf(wt, S.x, b4.x);
        S.y = fmaf(wt, S.y, b4.y);
        S.z = fmaf(wt, S.z, b4.z);
        S.w = fmaf(wt, S.w, b4.w);
    }
}

// ---------------------------------------------------------------------------
// Stage C (MFMA): Y = mask(qs@ks^T, diag) @ V + qs @ Sc. r/k/v inputs bf16.
// ---------------------------------------------------------------------------
__global__ __launch_bounds__(256) void chunk_out(const __hip_bfloat16* __restrict__ rb,
                                                 const __hip_bfloat16* __restrict__ kb,
                                                 const __hip_bfloat16* __restrict__ vb,
                                                 const float* __restrict__ lw,
                                                 const float* __restrict__ SbufT,
                                                 const float* __restrict__ tf,
                                                 float* __restrict__ y) {
    int bid = blockIdx.x;
    int c = bid & 15, h = (bid >> 4) & 15, b = bid >> 8;
    size_t gbase = ((size_t)(b * Tn + c * CL) * Hn + h) * 64;
    int tid = threadIdx.x;
    __shared__ alignas(16) __hip_bfloat16 qs[64][72];   // [t][ch]
    __shared__ alignas(16) __hip_bfloat16 ks[64][72];   // [tau][ch]
    __shared__ alignas(16) __hip_bfloat16 vsT[64][72];  // [v][tau]
    __shared__ alignas(16) __hip_bfloat16 scT[64][72];  // [v][ch]
    __shared__ alignas(16) float uni[64 * 68];          // linc, then asb
    __shared__ float wtp[4][64];
    __shared__ float diag[64];
    float (*linc)[68] = reinterpret_cast<float(*)[68]>(uni);
    __hip_bfloat16 (*asb)[72] = reinterpret_cast<__hip_bfloat16(*)[72]>(uni);
    int wave = tid >> 6, lane = tid & 63;
    {
        float acc = 0.f;
        #pragma unroll
        for (int i = 0; i < 16; i++) {
            int t = wave * 16 + i;
            acc += lw[gbase + (size_t)t * 1024 + lane];
            linc[t][lane] = acc;
        }
        wtp[wave][lane] = acc;
    }
    __syncthreads();
    {
        float off = 0.f;
        for (int g = 0; g < wave; g++) off += wtp[g][lane];
        #pragma unroll
        for (int i = 0; i < 16; i++) linc[wave * 16 + i][lane] += off;
    }
    __syncthreads();
    int t4 = tid >> 2, c0 = (tid & 3) * 16;
    float dpart = 0.f;
    #pragma unroll
    for (int i = 0; i < 4; i++) {
        int ch = c0 + i * 4;
        size_t ga = gbase + (size_t)t4 * 1024 + ch;
        ushort4 ru = *reinterpret_cast<const ushort4*>(rb + ga);
        ushort4 ku = *reinterpret_cast<const ushort4*>(kb + ga);
        ushort4 vu = *reinterpret_cast<const ushort4*>(vb + ga);
        float4 l4v = *reinterpret_cast<const float4*>(lw + ga);
        float4 u4 = *reinterpret_cast<const float4*>(tf + h * 64 + ch);
        float4 s4 = *reinterpret_cast<const float4*>(SbufT + (size_t)bid * 4096 + (size_t)t4 * 64 + ch);
        float rr[4] = {bfbits2f(ru.x), bfbits2f(ru.y), bfbits2f(ru.z), bfbits2f(ru.w)};
        float kkv[4] = {bfbits2f(ku.x), bfbits2f(ku.y), bfbits2f(ku.z), bfbits2f(ku.w)};
        float vv[4] = {bfbits2f(vu.x), bfbits2f(vu.y), bfbits2f(vu.z), bfbits2f(vu.w)};
        float lwv[4] = {l4v.x, l4v.y, l4v.z, l4v.w};
        float uu[4] = {u4.x, u4.y, u4.z, u4.w};
        float ss[4] = {s4.x, s4.y, s4.z, s4.w};
        #pragma unroll
        for (int j = 0; j < 4; j++) {
            float li = linc[t4][ch + j];
            qs[t4][ch + j] = __float2bfloat16(rr[j] * expf(li - lwv[j]));
            ks[t4][ch + j] = __float2bfloat16(kkv[j] * expf(-li));
            vsT[ch + j][t4] = __float2bfloat16(vv[j]);
            scT[t4][ch + j] = __float2bfloat16(ss[j]);   // row t4 = v
            dpart = fmaf(rr[j] * uu[j], kkv[j], dpart);
        }
    }
    dpart += __shfl_xor(dpart, 1);
    dpart += __shfl_xor(dpart, 2);
    if ((tid & 3) == 0) diag[t4] = dpart;
    __syncthreads();        // linc dead; asb may now overwrite uni
    int l15 = lane & 15, l4q = lane >> 4;
    #pragma unroll
    for (int nt = 0; nt < 4; nt++) {
        f32x4_t acc = {};
        if (nt <= wave) {
            #pragma unroll
            for (int kt = 0; kt < 2; kt++) {
                bf16x8_t a = *reinterpret_cast<const bf16x8_t*>(&qs[wave * 16 + l15][kt * 32 + l4q * 8]);
                bf16x8_t bb = *reinterpret_cast<const bf16x8_t*>(&ks[nt * 16 + l15][kt * 32 + l4q * 8]);
                acc = __builtin_amdgcn_mfma_f32_16x16x32_bf16(a, bb, acc, 0, 0, 0);
            }
        }
        #pragma unroll
        for (int q = 0; q < 4; q++) {
            int t = wave * 16 + l4q * 4 + q;
            int tau = nt * 16 + l15;
            float v = (tau < t) ? acc[q] : (tau == t ? diag[t] : 0.f);
            asb[t][tau] = __float2bfloat16(v);
        }
    }
    __syncthreads();
    #pragma unroll
    for (int nt = 0; nt < 4; nt++) {
        f32x4_t acc = {};
        int kmax = (wave >> 1) + 1;
        for (int kt = 0; kt < kmax; kt++) {
            bf16x8_t a = *reinterpret_cast<const bf16x8_t*>(&asb[wave * 16 + l15][kt * 32 + l4q * 8]);
            bf16x8_t bb = *reinterpret_cast<const bf16x8_t*>(&vsT[nt * 16 + l15][kt * 32 + l4q * 8]);
            acc = __builtin_amdgcn_mfma_f32_16x16x32_bf16(a, bb, acc, 0, 0, 0);
        }
        #pragma unroll
        for (int kt = 0; kt < 2; kt++) {
            bf16x8_t a = *reinterpret_cast<const bf16x8_t*>(&qs[wave * 16 + l15][kt * 32 + l4q * 8]);
            bf16x8_t bb = *reinterpret_cast<const bf16x8_t*>(&scT[nt * 16 + l15][kt * 32 + l4q * 8]);
            acc = __builtin_amdgcn_mfma_f32_16x16x32_bf16(a, bb, acc, 0, 0, 0);
        }
        #pragma unroll
        for (int q = 0; q < 4; q++) {
            int t = wave * 16 + l4q * 4 + q;
            y[gbase + (size_t)t * 1024 + nt * 16 + l15] = acc[q];
        }
    }
}

// ---------------------------------------------------------------------------
// GroupNorm per (bt,h) over 64 channels (after /8), *ln_w + ln_b, then *g.
// ---------------------------------------------------------------------------
__global__ __launch_bounds__(256) void gn_mul(const float* __restrict__ y,
                                              const __hip_bfloat16* __restrict__ g,
                                              const float* __restrict__ lnw,
                                              const float* __restrict__ lnb,
                                              __hip_bfloat16* __restrict__ fin) {
    int tid = threadIdx.x;
    int lane = tid & 63;
    int wv = tid >> 6;
    int grp = blockIdx.x * 4 + wv;    // bt*16 + h
    int h = grp & 15;
    size_t idx = (size_t)grp * 64 + lane;
    float val = y[idx] * 0.125f;
    float sum = val, sq = val * val;
    #pragma unroll
    for (int off = 32; off > 0; off >>= 1) {
        sum += __shfl_xor(sum, off, 64);
        sq  += __shfl_xor(sq,  off, 64);
    }
    float mu = sum * (1.f / 64.f);
    float var = sq * (1.f / 64.f) - mu * mu;
    float rs = rsqrtf(var + 1e-5f);
    float o = (val - mu) * rs * lnw[h * 64 + lane] + lnb[h * 64 + lane];
    fin[idx] = __float2bfloat16(o * __bfloat162float(g[idx]));
}

// ---------------------------------------------------------------------------
extern "C" void kernel_launch(void* const* d_in, const int* in_sizes, int n_in,
                              void* d_out, int out_size, void* d_ws, size_t ws_size,
                              hipStream_t stream) {
    (void)in_sizes; (void)n_in; (void)out_size; (void)ws_size;
    const float* x      = (const float*)d_in[0];
    const float* x_maa  = (const float*)d_in[1];
    const float* w_maa  = (const float*)d_in[2];
    const float* k_maa  = (const float*)d_in[3];
    const float* v_maa  = (const float*)d_in[4];
    const float* r_maa  = (const float*)d_in[5];
    const float* g_maa  = (const float*)d_in[6];
    const float* tm_w1  = (const float*)d_in[7];
    const float* tm_w2  = (const float*)d_in[8];
    const float* td_w1  = (const float*)d_in[9];
    const float* td_w2  = (const float*)d_in[10];
    const float* t_dec  = (const float*)d_in[11];
    const float* t_first= (const float*)d_in[12];
    const float* Wr     = (const float*)d_in[13];
    const float* Wk     = (const float*)d_in[14];
    const float* Wv     = (const float*)d_in[15];
    const float* Wg     = (const float*)d_in[16];
    const float* Wo     = (const float*)d_in[17];
    const float* ln_w   = (const float*)d_in[18];
    const float* ln_b   = (const float*)d_in[19];
    float* out = (float*)d_out;

    // Byte allocator, 256B aligned
    char* ws = (char*)d_ws;
    size_t off = 0;
    auto alloc = [&](size_t bytes) -> void* {
        void* p = ws + off;
        off = (off + bytes + 255) & ~(size_t)255;
        return p;
    };
    __hip_bfloat16* mixin = (__hip_bfloat16*)alloc(BTC * 2);  // alias: rb (bf16)
    float* mix160 = (float*)alloc((size_t)BT * 160 * 4);
    float* wxr    = (float*)alloc(BTC * 4);            // wx -> BcB -> ybuf
    __hip_bfloat16* kxb = (__hip_bfloat16*)alloc(BTC * 2);  // alias: fin
    __hip_bfloat16* vxb = (__hip_bfloat16*)alloc(BTC * 2);
    __hip_bfloat16* rxb = (__hip_bfloat16*)alloc(BTC * 2);  // rxb+gxb -> SbufT (16MB)
    __hip_bfloat16* gxb = (__hip_bfloat16*)alloc(BTC * 2);
    __hip_bfloat16* kb  = (__hip_bfloat16*)alloc(BTC * 2);
    __hip_bfloat16* vb  = (__hip_bfloat16*)alloc(BTC * 2);
    __hip_bfloat16* gb  = (__hip_bfloat16*)alloc(BTC * 2);
    float* wl1 = (float*)alloc((size_t)BT * 64 * 4);   // alias: WtB
    float* lwb = (float*)alloc(BTC * 4);
    __hip_bfloat16* WrT = (__hip_bfloat16*)alloc((size_t)Cn * Cn * 2);
    __hip_bfloat16* WkT = (__hip_bfloat16*)alloc((size_t)Cn * Cn * 2);
    __hip_bfloat16* WvT = (__hip_bfloat16*)alloc((size_t)Cn * Cn * 2);
    __hip_bfloat16* WgT = (__hip_bfloat16*)alloc((size_t)Cn * Cn * 2);
    __hip_bfloat16* WoT = (__hip_bfloat16*)alloc((size_t)Cn * Cn * 2);
    __hip_bfloat16* tmw1T = (__hip_bfloat16*)alloc((size_t)160 * Cn * 2);
    float* skpart = (float*)alloc((size_t)8 * BT * 64 * 4);    // decay split-K partials (8MB)
    float* lorapart = (float*)alloc((size_t)4 * BT * 160 * 4); // LoRA1 split-K partials (10.5MB)
    // Aliases (stream-ordered; producers complete before reuse):
    __hip_bfloat16* rb = mixin;    // r projection (mixin dead after LoRA1)
    float* BcB   = wxr;            // chunk contributions (wx dead after splitk)
    float* ybuf  = wxr;            // recurrence out (BcB dead after chunk_scan)
    float* WtB   = wl1;            // chunk decay totals (wl1 dead after decay GEMM)
    float* SbufT = (float*)rxb;    // entry states (transposed), spans rxb+gxb
    __hip_bfloat16* fin = kxb;     // gn output (kxb dead after projections)

    dim3 blk(256);
    // weight transpose+convert (one dispatch for the 5 square weights)
    transp5<<<dim3(32, 32, 5), blk, 0, stream>>>(Wr, Wk, Wv, Wg, Wo,
                                                 WrT, WkT, WvT, WgT, WoT);
    transp_bf16<<<dim3(5, 32), blk, 0, stream>>>(tm_w1, tmw1T, Cn, 160);
    // token-mix LoRA1 (bf16 MFMA split-K over 4 K-parts, 512 blocks)
    prep_mixin<<<dim3((unsigned)(BTC / 1024)), blk, 0, stream>>>(x, x_maa, mixin);
    gemm_mfma_sk<4><<<dim3(2, 64, 4), blk, 0, stream>>>(mixin, tmw1T, lorapart, BT, 160, Cn);
    splitk_reduce_tanh<4><<<dim3((BT * 160 + 255) / 256), blk, 0, stream>>>(
        lorapart, mix160, BT * 160, (size_t)BT * 160);
    deltas_mix<<<dim3(BT / 4), blk, 0, stream>>>(x, mix160, tm_w2,
                                                 w_maa, k_maa, v_maa, r_maa, g_maa,
                                                 wxr, kxb, vxb, rxb, gxb);
    // projections: ONE grouped dispatch (r,k,v,g), 64x128 tile, 2048 blocks
    gemm_qkvg<<<dim3(8, 64, 4), blk, 0, stream>>>(rxb, kxb, vxb, gxb,
                                                  WrT, WkT, WvT, WgT,
                                                  rb, kb, vb, gb, BT, Cn, Cn);
    // decay LoRA1 (f32 split-K, 512 blocks) + fused reduce/tanh
    gemm_f32_splitk<8><<<dim3(8, 64), blk, 0, stream>>>(wxr, td_w1, skpart, BT, 64, Cn);
    splitk_reduce_tanh<8><<<dim3(BT * 64 / 256), blk, 0, stream>>>(skpart, wl1, BT * 64,
                                                                   (size_t)BT * 64);
    // decay GEMM2 (f32, precision-sensitive)
    gemm_f32<3><<<dim3(16, 64), blk, 0, stream>>>(wl1, td_w2, lwb, BT, Cn, 64, t_dec);
    // chunked scan (MFMA)
    chunk_summary<<<dim3(Bn * Hn * NC), blk, 0, stream>>>(kb, vb, lwb, BcB, WtB);
    chunk_scan<<<dim3(Bn * Hn * 4), blk, 0, stream>>>(BcB, WtB, SbufT);
    chunk_out<<<dim3(Bn * Hn * NC), blk, 0, stream>>>(rb, kb, vb, lwb, SbufT, t_first, ybuf);
    // epilogue
    gn_mul<<<dim3(BT * Hn / 4), blk, 0, stream>>>(ybuf, gb, ln_w, ln_b, fin);
    gemm_mfma_gl<<<dim3(8, 64), blk, 0, stream>>>(fin, WoT, out, BT, Cn, Cn);
}

// Round 12
// 216.045 us; speedup vs baseline: 1.1841x; 1.0309x over previous
//
#include <hip/hip_runtime.h>
#include <hip/hip_bf16.h>
#include <math.h>
#include <stdint.h>

// Problem constants
constexpr int Bn = 4, Tn = 1024, Cn = 1024, Hn = 16;
constexpr int BT = Bn * Tn;                 // 4096
constexpr long long BTC = (long long)BT * Cn;  // 4M elements
constexpr int CL = 64;                      // chunk length
constexpr int NC = Tn / CL;                 // 16 chunks

typedef __bf16 bf16x8_t __attribute__((ext_vector_type(8)));
typedef float f32x4_t __attribute__((ext_vector_type(4)));
typedef unsigned short us8_t __attribute__((ext_vector_type(8)));

__device__ __forceinline__ unsigned short f2bf_bits(float v) {
    __hip_bfloat16 h = __float2bfloat16(v);
    return *reinterpret_cast<unsigned short*>(&h);
}
__device__ __forceinline__ float bfbits2f(unsigned short u) {
    unsigned int x = (unsigned int)u << 16;
    return __uint_as_float(x);
}

// Direct global->LDS 16B/lane (wave-uniform LDS base + lane*16). CK-style casts.
__device__ __forceinline__ void gload16(const void* g, void* l) {
    auto const* gp = reinterpret_cast<const unsigned int __attribute__((address_space(1)))*>(
        reinterpret_cast<uintptr_t>(g));
    auto* lp = reinterpret_cast<unsigned int __attribute__((address_space(3)))*>(
        reinterpret_cast<uintptr_t>(l));
    __builtin_amdgcn_global_load_lds(gp, lp, 16, 0, 0);
}

// ---------------------------------------------------------------------------
// mix input for the token-mix LoRA (x4 vectorized)
// ---------------------------------------------------------------------------
__global__ __launch_bounds__(256) void prep_mixin(const float* __restrict__ x,
                                                  const float* __restrict__ x_maa,
                                                  __hip_bfloat16* __restrict__ out) {
    long long q = (long long)blockIdx.x * 256 + threadIdx.x;   // quad index
    if (q * 4 >= BTC) return;
    long long idx = q * 4;
    int c = (int)(idx & (Cn - 1));
    long long bt = idx >> 10;
    int t = (int)(bt & (Tn - 1));
    float4 xv = *reinterpret_cast<const float4*>(x + idx);
    float4 xp = (t > 0) ? *reinterpret_cast<const float4*>(x + idx - Cn)
                        : make_float4(0.f, 0.f, 0.f, 0.f);
    float4 ma = *reinterpret_cast<const float4*>(x_maa + c);
    ushort4 o;
    o.x = f2bf_bits(xv.x + (xp.x - xv.x) * ma.x);
    o.y = f2bf_bits(xv.y + (xp.y - xv.y) * ma.y);
    o.z = f2bf_bits(xv.z + (xp.z - xv.z) * ma.z);
    o.w = f2bf_bits(xv.w + (xp.w - xv.w) * ma.w);
    *reinterpret_cast<ushort4*>(out + idx) = o;
}

// ---------------------------------------------------------------------------
// Transpose + convert, 5 square weights in one dispatch (z selects matrix).
// ---------------------------------------------------------------------------
__global__ __launch_bounds__(256) void transp5(const float* __restrict__ W0,
                                               const float* __restrict__ W1,
                                               const float* __restrict__ W2,
                                               const float* __restrict__ W3,
                                               const float* __restrict__ W4,
                                               __hip_bfloat16* __restrict__ T0,
                                               __hip_bfloat16* __restrict__ T1,
                                               __hip_bfloat16* __restrict__ T2,
                                               __hip_bfloat16* __restrict__ T3,
                                               __hip_bfloat16* __restrict__ T4) {
    int z = blockIdx.z;
    const float* W = (z == 0) ? W0 : (z == 1) ? W1 : (z == 2) ? W2 : (z == 3) ? W3 : W4;
    __hip_bfloat16* Wt = (z == 0) ? T0 : (z == 1) ? T1 : (z == 2) ? T2 : (z == 3) ? T3 : T4;
    __shared__ float tile[32][33];
    int c0 = blockIdx.x * 32, r0 = blockIdx.y * 32;
    int tx = threadIdx.x & 31, ty = threadIdx.x >> 5;
    #pragma unroll
    for (int i = 0; i < 4; i++)
        tile[ty + 8 * i][tx] = W[(size_t)(r0 + ty + 8 * i) * Cn + c0 + tx];
    __syncthreads();
    #pragma unroll
    for (int i = 0; i < 4; i++)
        Wt[(size_t)(c0 + ty + 8 * i) * Cn + r0 + tx] = __float2bfloat16(tile[tx][ty + 8 * i]);
}

// Generic single transpose (tm_w1: [Cn,160] -> [160,Cn])
__global__ __launch_bounds__(256) void transp_bf16(const float* __restrict__ W,
                                                   __hip_bfloat16* __restrict__ Wt,
                                                   int R, int Cc) {
    __shared__ float tile[32][33];
    int c0 = blockIdx.x * 32, r0 = blockIdx.y * 32;
    int tx = threadIdx.x & 31, ty = threadIdx.x >> 5;
    #pragma unroll
    for (int i = 0; i < 4; i++)
        tile[ty + 8 * i][tx] = W[(size_t)(r0 + ty + 8 * i) * Cc + c0 + tx];
    __syncthreads();
    #pragma unroll
    for (int i = 0; i < 4; i++)
        Wt[(size_t)(c0 + ty + 8 * i) * R + r0 + tx] = __float2bfloat16(tile[tx][ty + 8 * i]);
}

// ---------------------------------------------------------------------------
// f32 tiled GEMM (decay LoRA GEMM2, precision-sensitive): C = A[M,K]@B[K,N].
// EPI: 3 logdecay (-exp(extra[col]+acc))
// ---------------------------------------------------------------------------
template <int EPI>
__global__ __launch_bounds__(256) void gemm_f32(const float* __restrict__ A,
                                                const float* __restrict__ Bm,
                                                float* __restrict__ C,
                                                int M, int N, int K,
                                                const float* __restrict__ extra) {
    __shared__ float As[16][64];
    __shared__ float Bs[16][64];
    int tid = threadIdx.x;
    int m0 = blockIdx.y * 64, n0 = blockIdx.x * 64;
    int tx = tid & 15, ty = tid >> 4;
    int ar = tid >> 2, ac = (tid & 3) * 4;
    int br = tid >> 4, bc = (tid & 15) * 4;
    float acc[4][4] = {};

    for (int k0 = 0; k0 < K; k0 += 16) {
        const float* ap = A + (size_t)(m0 + ar) * K + k0 + ac;
        float4 av = *reinterpret_cast<const float4*>(ap);
        As[ac + 0][ar] = av.x; As[ac + 1][ar] = av.y;
        As[ac + 2][ar] = av.z; As[ac + 3][ar] = av.w;
        float4 bv = *reinterpret_cast<const float4*>(Bm + (size_t)(k0 + br) * N + n0 + bc);
        *reinterpret_cast<float4*>(&Bs[br][bc]) = bv;
        __syncthreads();
        #pragma unroll
        for (int kk = 0; kk < 16; kk++) {
            float4 a4 = *reinterpret_cast<const float4*>(&As[kk][ty * 4]);
            float4 b4 = *reinterpret_cast<const float4*>(&Bs[kk][tx * 4]);
            float aa[4] = {a4.x, a4.y, a4.z, a4.w};
            float bb[4] = {b4.x, b4.y, b4.z, b4.w};
            #pragma unroll
            for (int i = 0; i < 4; i++)
                #pragma unroll
                for (int j = 0; j < 4; j++)
                    acc[i][j] = fmaf(aa[i], bb[j], acc[i][j]);
        }
        __syncthreads();
    }

    #pragma unroll
    for (int i = 0; i < 4; i++) {
        int row = m0 + ty * 4 + i;
        #pragma unroll
        for (int j = 0; j < 4; j++) {
            int col = n0 + tx * 4 + j;
            float v = acc[i][j];
            if (EPI == 3) v = -expf(extra[col] + v);
            C[(size_t)row * N + col] = v;
        }
    }
}

// ---------------------------------------------------------------------------
// Split-K f32 GEMM for the decay LoRA1 ([4096,1024]@[1024,64], N==64).
// ---------------------------------------------------------------------------
template <int KS>
__global__ __launch_bounds__(256) void gemm_f32_splitk(const float* __restrict__ A,
                                                       const float* __restrict__ Bm,
                                                       float* __restrict__ part,
                                                       int M, int N, int K) {
    __shared__ float As[16][64];
    __shared__ float Bs[16][64];
    int tid = threadIdx.x;
    int kp = blockIdx.x;
    int m0 = blockIdx.y * 64;
    int kbeg = kp * (K / KS), kend = kbeg + K / KS;
    int tx = tid & 15, ty = tid >> 4;
    int ar = tid >> 2, ac = (tid & 3) * 4;
    int br = tid >> 4, bc = (tid & 15) * 4;
    float acc[4][4] = {};

    for (int k0 = kbeg; k0 < kend; k0 += 16) {
        float4 av = *reinterpret_cast<const float4*>(A + (size_t)(m0 + ar) * K + k0 + ac);
        As[ac + 0][ar] = av.x; As[ac + 1][ar] = av.y;
        As[ac + 2][ar] = av.z; As[ac + 3][ar] = av.w;
        *reinterpret_cast<float4*>(&Bs[br][bc]) =
            *reinterpret_cast<const float4*>(Bm + (size_t)(k0 + br) * N + bc);
        __syncthreads();
        #pragma unroll
        for (int kk = 0; kk < 16; kk++) {
            float4 a4 = *reinterpret_cast<const float4*>(&As[kk][ty * 4]);
            float4 b4 = *reinterpret_cast<const float4*>(&Bs[kk][tx * 4]);
            float aa[4] = {a4.x, a4.y, a4.z, a4.w};
            float bb[4] = {b4.x, b4.y, b4.z, b4.w};
            #pragma unroll
            for (int i = 0; i < 4; i++)
                #pragma unroll
                for (int j = 0; j < 4; j++)
                    acc[i][j] = fmaf(aa[i], bb[j], acc[i][j]);
        }
        __syncthreads();
    }
    #pragma unroll
    for (int i = 0; i < 4; i++) {
        int row = m0 + ty * 4 + i;
        #pragma unroll
        for (int j = 0; j < 4; j++)
            part[((size_t)kp * M + row) * N + tx * 4 + j] = acc[i][j];
    }
}

// Reduce KS partials + tanh
template <int KS>
__global__ __launch_bounds__(256) void splitk_reduce_tanh(const float* __restrict__ part,
                                                          float* __restrict__ outp,
                                                          int total, size_t stride) {
    int i = blockIdx.x * 256 + threadIdx.x;
    if (i >= total) return;
    float s = 0.f;
    #pragma unroll
    for (int kp = 0; kp < KS; kp++) s += part[kp * stride + i];
    outp[i] = tanhf(s);
}

// ---------------------------------------------------------------------------
// Split-K bf16 MFMA GEMM for token-mix LoRA1 ([4096,1024]@[1024,160]).
// ---------------------------------------------------------------------------
template <int KS>
__global__ __launch_bounds__(256) void gemm_mfma_sk(const __hip_bfloat16* __restrict__ A,
                                                    const __hip_bfloat16* __restrict__ Bt,
                                                    float* __restrict__ part,
                                                    int M, int N, int K) {
    __shared__ alignas(16) unsigned short As[64 * 64];
    __shared__ alignas(16) unsigned short Bs[128 * 64];
    int tid = threadIdx.x;
    int m0 = blockIdx.y * 64, n0 = blockIdx.x * 128;
    int kp = blockIdx.z;
    int kbeg = kp * (K / KS), kend = kbeg + K / KS;
    int wave = tid >> 6, lane = tid & 63;
    int wm = (wave & 1) * 32, wn = (wave >> 1) * 64;
    int l15 = lane & 15, l4 = lane >> 4;
    f32x4_t acc[2][4] = {};

    for (int k0 = kbeg; k0 < kend; k0 += 64) {
        #pragma unroll
        for (int p = 0; p < 2; p++) {
            int cch = tid + p * 256;
            int row = cch >> 3, slot = cch & 7;
            int s2 = slot ^ (row & 7);
            *reinterpret_cast<us8_t*>(&As[row * 64 + s2 * 8]) =
                *reinterpret_cast<const us8_t*>(&A[(size_t)(m0 + row) * K + k0 + slot * 8]);
        }
        #pragma unroll
        for (int p = 0; p < 4; p++) {
            int cch = tid + p * 256;
            int row = cch >> 3, slot = cch & 7;
            int s2 = slot ^ (row & 7);
            int rowg = n0 + row; if (rowg > N - 1) rowg = N - 1;  // clamp
            *reinterpret_cast<us8_t*>(&Bs[row * 64 + s2 * 8]) =
                *reinterpret_cast<const us8_t*>(&Bt[(size_t)rowg * K + k0 + slot * 8]);
        }
        __syncthreads();
        #pragma unroll
        for (int kw = 0; kw < 2; kw++) {
            int slot = kw * 4 + l4;
            bf16x8_t af[2], bfr[4];
            #pragma unroll
            for (int f = 0; f < 2; f++) {
                int ar = wm + f * 16 + l15;
                af[f] = *reinterpret_cast<const bf16x8_t*>(&As[ar * 64 + (slot ^ (ar & 7)) * 8]);
            }
            #pragma unroll
            for (int f = 0; f < 4; f++) {
                int br = wn + f * 16 + l15;
                bfr[f] = *reinterpret_cast<const bf16x8_t*>(&Bs[br * 64 + (slot ^ (br & 7)) * 8]);
            }
            #pragma unroll
            for (int i = 0; i < 2; i++)
                #pragma unroll
                for (int j = 0; j < 4; j++)
                    acc[i][j] = __builtin_amdgcn_mfma_f32_16x16x32_bf16(af[i], bfr[j], acc[i][j], 0, 0, 0);
        }
        __syncthreads();
    }

    #pragma unroll
    for (int i = 0; i < 2; i++) {
        int rbase = m0 + wm + i * 16 + l4 * 4;
        #pragma unroll
        for (int j = 0; j < 4; j++) {
            int col = n0 + wn + j * 16 + l15;
            if (col < N) {
                #pragma unroll
                for (int q = 0; q < 4; q++)
                    part[((size_t)kp * M + rbase + q) * N + col] = acc[i][j][q];
            }
        }
    }
}

// ---------------------------------------------------------------------------
// GROUPED bf16 MFMA GEMM: 4 projections (r,k,v,g) in ONE dispatch.
// 64x128 tile; grid (x=m-tile 64, y=n-tile 8, z=group 4) so XCD = m%8:
// each XCD's L2 holds the full B panel (2 MB) + its A slice (1 MB) -> L2-hit
// re-reads instead of HBM. global_load_lds staging. Outputs bf16; z==3 silu.
// ---------------------------------------------------------------------------
__global__ __launch_bounds__(256) void gemm_qkvg(const __hip_bfloat16* __restrict__ A0,
                                                 const __hip_bfloat16* __restrict__ A1,
                                                 const __hip_bfloat16* __restrict__ A2,
                                                 const __hip_bfloat16* __restrict__ A3,
                                                 const __hip_bfloat16* __restrict__ B0,
                                                 const __hip_bfloat16* __restrict__ B1,
                                                 const __hip_bfloat16* __restrict__ B2,
                                                 const __hip_bfloat16* __restrict__ B3,
                                                 __hip_bfloat16* __restrict__ C0,
                                                 __hip_bfloat16* __restrict__ C1,
                                                 __hip_bfloat16* __restrict__ C2,
                                                 __hip_bfloat16* __restrict__ C3,
                                                 int M, int N, int K) {
    int g = blockIdx.z;
    const __hip_bfloat16* A  = (g == 0) ? A0 : (g == 1) ? A1 : (g == 2) ? A2 : A3;
    const __hip_bfloat16* Bt = (g == 0) ? B0 : (g == 1) ? B1 : (g == 2) ? B2 : B3;
    __hip_bfloat16* Co = (g == 0) ? C0 : (g == 1) ? C1 : (g == 2) ? C2 : C3;
    __shared__ alignas(16) unsigned short As[64 * 64];
    __shared__ alignas(16) unsigned short Bs[128 * 64];
    int tid = threadIdx.x;
    int m0 = blockIdx.x * 64, n0 = blockIdx.y * 128;   // m fastest -> XCD=m%8
    int wave = tid >> 6, lane = tid & 63;
    int wm = (wave & 1) * 32, wn = (wave >> 1) * 64;
    int l15 = lane & 15, l4 = lane >> 4;
    int lrow = lane >> 3, ls2 = lane & 7;
    f32x4_t acc[2][4] = {};

    for (int k0 = 0; k0 < K; k0 += 64) {
        #pragma unroll
        for (int ci = 0; ci < 2; ci++) {
            int r0 = wave * 16 + ci * 8;
            int row = r0 + lrow;
            int gs = ls2 ^ (row & 7);
            gload16(&A[(size_t)(m0 + row) * K + k0 + gs * 8], &As[r0 * 64]);
        }
        #pragma unroll
        for (int ci = 0; ci < 4; ci++) {
            int r0 = wave * 32 + ci * 8;
            int row = r0 + lrow;
            int gs = ls2 ^ (row & 7);
            gload16(&Bt[(size_t)(n0 + row) * K + k0 + gs * 8], &Bs[r0 * 64]);
        }
        __syncthreads();
        #pragma unroll
        for (int kw = 0; kw < 2; kw++) {
            int slot = kw * 4 + l4;
            bf16x8_t af[2], bfr[4];
            #pragma unroll
            for (int f = 0; f < 2; f++) {
                int ar = wm + f * 16 + l15;
                af[f] = *reinterpret_cast<const bf16x8_t*>(&As[ar * 64 + (slot ^ (ar & 7)) * 8]);
            }
            #pragma unroll
            for (int f = 0; f < 4; f++) {
                int br = wn + f * 16 + l15;
                bfr[f] = *reinterpret_cast<const bf16x8_t*>(&Bs[br * 64 + (slot ^ (br & 7)) * 8]);
            }
            #pragma unroll
            for (int i = 0; i < 2; i++)
                #pragma unroll
                for (int j = 0; j < 4; j++)
                    acc[i][j] = __builtin_amdgcn_mfma_f32_16x16x32_bf16(af[i], bfr[j], acc[i][j], 0, 0, 0);
        }
        __syncthreads();
    }

    #pragma unroll
    for (int i = 0; i < 2; i++) {
        int rbase = m0 + wm + i * 16 + l4 * 4;
        #pragma unroll
        for (int j = 0; j < 4; j++) {
            int col = n0 + wn + j * 16 + l15;
            #pragma unroll
            for (int q = 0; q < 4; q++) {
                float v = acc[i][j][q];
                if (g == 3) v = v / (1.f + expf(-v));
                Co[(size_t)(rbase + q) * N + col] = __float2bfloat16(v);
            }
        }
    }
}

// Wo projection (single, gl-staged, 64x128 tile, m-fastest grid), f32 out
__global__ __launch_bounds__(256) void gemm_mfma_gl(const __hip_bfloat16* __restrict__ A,
                                                    const __hip_bfloat16* __restrict__ Bt,
                                                    float* __restrict__ Cout,
                                                    int M, int N, int K) {
    __shared__ alignas(16) unsigned short As[64 * 64];
    __shared__ alignas(16) unsigned short Bs[128 * 64];
    int tid = threadIdx.x;
    int m0 = blockIdx.x * 64, n0 = blockIdx.y * 128;   // m fastest -> XCD=m%8
    int wave = tid >> 6, lane = tid & 63;
    int wm = (wave & 1) * 32, wn = (wave >> 1) * 64;
    int l15 = lane & 15, l4 = lane >> 4;
    int lrow = lane >> 3, ls2 = lane & 7;
    f32x4_t acc[2][4] = {};

    for (int k0 = 0; k0 < K; k0 += 64) {
        #pragma unroll
        for (int ci = 0; ci < 2; ci++) {
            int r0 = wave * 16 + ci * 8;
            int row = r0 + lrow;
            int gs = ls2 ^ (row & 7);
            gload16(&A[(size_t)(m0 + row) * K + k0 + gs * 8], &As[r0 * 64]);
        }
        #pragma unroll
        for (int ci = 0; ci < 4; ci++) {
            int r0 = wave * 32 + ci * 8;
            int row = r0 + lrow;
            int gs = ls2 ^ (row & 7);
            gload16(&Bt[(size_t)(n0 + row) * K + k0 + gs * 8], &Bs[r0 * 64]);
        }
        __syncthreads();
        #pragma unroll
        for (int kw = 0; kw < 2; kw++) {
            int slot = kw * 4 + l4;
            bf16x8_t af[2], bfr[4];
            #pragma unroll
            for (int f = 0; f < 2; f++) {
                int ar = wm + f * 16 + l15;
                af[f] = *reinterpret_cast<const bf16x8_t*>(&As[ar * 64 + (slot ^ (ar & 7)) * 8]);
            }
            #pragma unroll
            for (int f = 0; f < 4; f++) {
                int br = wn + f * 16 + l15;
                bfr[f] = *reinterpret_cast<const bf16x8_t*>(&Bs[br * 64 + (slot ^ (br & 7)) * 8]);
            }
            #pragma unroll
            for (int i = 0; i < 2; i++)
                #pragma unroll
                for (int j = 0; j < 4; j++)
                    acc[i][j] = __builtin_amdgcn_mfma_f32_16x16x32_bf16(af[i], bfr[j], acc[i][j], 0, 0, 0);
        }
        __syncthreads();
    }

    #pragma unroll
    for (int i = 0; i < 2; i++) {
        int rbase = m0 + wm + i * 16 + l4 * 4;
        #pragma unroll
        for (int j = 0; j < 4; j++) {
            int col = n0 + wn + j * 16 + l15;
            #pragma unroll
            for (int q = 0; q < 4; q++)
                Cout[(size_t)(rbase + q) * N + col] = acc[i][j][q];
        }
    }
}

// ---------------------------------------------------------------------------
// 5 mix deltas fused with wx/kx/vx/rx/gx build.
// ---------------------------------------------------------------------------
__global__ __launch_bounds__(256) void deltas_mix(const float* __restrict__ x,
                                                  const float* __restrict__ mix160,
                                                  const float* __restrict__ w2,
                                                  const float* __restrict__ wmaa,
                                                  const float* __restrict__ kmaa,
                                                  const float* __restrict__ vmaa,
                                                  const float* __restrict__ rmaa,
                                                  const float* __restrict__ gmaa,
                                                  float* __restrict__ wx,
                                                  __hip_bfloat16* __restrict__ kxb,
                                                  __hip_bfloat16* __restrict__ vxb,
                                                  __hip_bfloat16* __restrict__ rxb,
                                                  __hip_bfloat16* __restrict__ gxb) {
    int tid = threadIdx.x;
    int c4 = tid * 4;
    int r0 = blockIdx.x * 4;
    const float* mrow = mix160 + (size_t)r0 * 160;   // block-uniform base
    float xv[4][4], sx[4][4];
    #pragma unroll
    for (int r = 0; r < 4; r++) {
        int row = r0 + r;
        int t = row & (Tn - 1);
        size_t idx = (size_t)row * Cn + c4;
        float4 xvv = *reinterpret_cast<const float4*>(x + idx);
        float4 xp = (t > 0) ? *reinterpret_cast<const float4*>(x + idx - Cn)
                            : make_float4(0.f, 0.f, 0.f, 0.f);
        xv[r][0] = xvv.x; xv[r][1] = xvv.y; xv[r][2] = xvv.z; xv[r][3] = xvv.w;
        sx[r][0] = xp.x - xvv.x; sx[r][1] = xp.y - xvv.y;
        sx[r][2] = xp.z - xvv.z; sx[r][3] = xp.w - xvv.w;
    }
    #pragma unroll
    for (int f = 0; f < 5; f++) {
        float acc[4][4] = {};
        for (int dd = 0; dd < 32; dd++) {
            float4 wv = *reinterpret_cast<const float4*>(w2 + (size_t)(f * 32 + dd) * Cn + c4);
            float wvv[4] = {wv.x, wv.y, wv.z, wv.w};
            #pragma unroll
            for (int r = 0; r < 4; r++) {
                float ms = mrow[r * 160 + f * 32 + dd];    // scalar (s_load)
                #pragma unroll
                for (int j = 0; j < 4; j++)
                    acc[r][j] = fmaf(ms, wvv[j], acc[r][j]);
            }
        }
        const float* maa = (f == 0) ? wmaa : (f == 1) ? kmaa : (f == 2) ? vmaa
                         : (f == 3) ? rmaa : gmaa;
        float4 mv4 = *reinterpret_cast<const float4*>(maa + c4);
        float mvv[4] = {mv4.x, mv4.y, mv4.z, mv4.w};
        #pragma unroll
        for (int r = 0; r < 4; r++) {
            size_t idx = (size_t)(r0 + r) * Cn + c4;
            float val[4];
            #pragma unroll
            for (int j = 0; j < 4; j++)
                val[j] = xv[r][j] + sx[r][j] * (mvv[j] + acc[r][j]);
            if (f == 0) {
                *reinterpret_cast<float4*>(wx + idx) =
                    make_float4(val[0], val[1], val[2], val[3]);
            } else {
                ushort4 o;
                o.x = f2bf_bits(val[0]); o.y = f2bf_bits(val[1]);
                o.z = f2bf_bits(val[2]); o.w = f2bf_bits(val[3]);
                __hip_bfloat16* dst = (f == 1) ? kxb : (f == 2) ? vxb : (f == 3) ? rxb : gxb;
                *reinterpret_cast<ushort4*>(dst + idx) = o;
            }
        }
    }
}

// ---------------------------------------------------------------------------
// Chunked WKV stage A (MFMA): per (b,h,chunk). k/v inputs bf16.
// ---------------------------------------------------------------------------
__global__ __launch_bounds__(256) void chunk_summary(const __hip_bfloat16* __restrict__ kb,
                                                     const __hip_bfloat16* __restrict__ vb,
                                                     const float* __restrict__ lw,
                                                     float* __restrict__ Bc,
                                                     float* __restrict__ Wtot) {
    int bid = blockIdx.x;
    int c = bid & 15, h = (bid >> 4) & 15, b = bid >> 8;
    size_t gbase = ((size_t)(b * Tn + c * CL) * Hn + h) * 64;
    int tid = threadIdx.x;
    __shared__ float linc[64][68];
    __shared__ float wtp[4][64];
    __shared__ alignas(16) __hip_bfloat16 kdT[64][72];  // [ch][tau]
    __shared__ alignas(16) __hip_bfloat16 vsT[64][72];  // [v][tau]
    int wave = tid >> 6, lane = tid & 63;
    {
        float acc = 0.f;
        #pragma unroll
        for (int i = 0; i < 16; i++) {
            int t = wave * 16 + i;
            acc += lw[gbase + (size_t)t * 1024 + lane];
            linc[t][lane] = acc;
        }
        wtp[wave][lane] = acc;
    }
    __syncthreads();
    {
        float off = 0.f;
        for (int g = 0; g < wave; g++) off += wtp[g][lane];
        #pragma unroll
        for (int i = 0; i < 16; i++) linc[wave * 16 + i][lane] += off;
    }
    __syncthreads();
    int t4 = tid >> 2, c0 = (tid & 3) * 16;
    #pragma unroll
    for (int i = 0; i < 4; i++) {
        int ch = c0 + i * 4;
        size_t ga = gbase + (size_t)t4 * 1024 + ch;
        ushort4 ku = *reinterpret_cast<const ushort4*>(kb + ga);
        ushort4 vu = *reinterpret_cast<const ushort4*>(vb + ga);
        float kk[4] = {bfbits2f(ku.x), bfbits2f(ku.y), bfbits2f(ku.z), bfbits2f(ku.w)};
        float vv[4] = {bfbits2f(vu.x), bfbits2f(vu.y), bfbits2f(vu.z), bfbits2f(vu.w)};
        #pragma unroll
        for (int j = 0; j < 4; j++) {
            float li = linc[t4][ch + j];
            float lend = linc[63][ch + j];
            kdT[ch + j][t4] = __float2bfloat16(kk[j] * expf(lend - li));
            vsT[ch + j][t4] = __float2bfloat16(vv[j]);
        }
    }
    if (tid < 64) Wtot[(size_t)bid * 64 + tid] = expf(linc[63][tid]);
    __syncthreads();
    int l15 = lane & 15, l4q = lane >> 4;
    #pragma unroll
    for (int nt = 0; nt < 4; nt++) {
        f32x4_t acc = {};
        #pragma unroll
        for (int kt = 0; kt < 2; kt++) {
            bf16x8_t a = *reinterpret_cast<const bf16x8_t*>(&kdT[wave * 16 + l15][kt * 32 + l4q * 8]);
            bf16x8_t bb = *reinterpret_cast<const bf16x8_t*>(&vsT[nt * 16 + l15][kt * 32 + l4q * 8]);
            acc = __builtin_amdgcn_mfma_f32_16x16x32_bf16(a, bb, acc, 0, 0, 0);
        }
        #pragma unroll
        for (int q = 0; q < 4; q++) {
            int krow = wave * 16 + l4q * 4 + q;
            Bc[(size_t)bid * 4096 + (size_t)krow * 64 + nt * 16 + l15] = acc[q];
        }
    }
}

// ---------------------------------------------------------------------------
// Stage B: sequential scan over NC=16 chunk states; TRANSPOSED entry states.
// ---------------------------------------------------------------------------
__global__ __launch_bounds__(256) void chunk_scan(const float* __restrict__ Bc,
                                                  const float* __restrict__ Wtot,
                                                  float* __restrict__ SbufT) {
    int bid = blockIdx.x;
    int bh = bid >> 2, vg = bid & 3;
    int kk = threadIdx.x >> 2;
    int v = vg * 16 + (threadIdx.x & 3) * 4;
    float4 S = make_float4(0.f, 0.f, 0.f, 0.f);
    for (int c = 0; c < NC; c++) {
        size_t base = (size_t)(bh * NC + c) * 4096;
        SbufT[base + (size_t)(v + 0) * 64 + kk] = S.x;
        SbufT[base + (size_t)(v + 1) * 64 + kk] = S.y;
        SbufT[base + (size_t)(v + 2) * 64 + kk] = S.z;
        SbufT[base + (size_t)(v + 3) * 64 + kk] = S.w;
        float wt = Wtot[(size_t)(bh * NC + c) * 64 + kk];
        float4 b4 = *reinterpret_cast<const float4*>(Bc + base + (size_t)kk * 64 + v);
        S.x = fmaf(wt, S.x, b4.x);
        S.y = fmaf(wt, S.y, b4.y);
        S.z = fmaf(wt, S.z, b4.z);
        S.w = fmaf(wt, S.w, b4.w);
    }
}

// ---------------------------------------------------------------------------
// Stage C (MFMA): Y = mask(qs@ks^T, diag) @ V + qs @ Sc. r/k/v inputs bf16.
// ---------------------------------------------------------------------------
__global__ __launch_bounds__(256) void chunk_out(const __hip_bfloat16* __restrict__ rb,
                                                 const __hip_bfloat16* __restrict__ kb,
                                                 const __hip_bfloat16* __restrict__ vb,
                                                 const float* __restrict__ lw,
                                                 const float* __restrict__ SbufT,
                                                 const float* __restrict__ tf,
                                                 float* __restrict__ y) {
    int bid = blockIdx.x;
    int c = bid & 15, h = (bid >> 4) & 15, b = bid >> 8;
    size_t gbase = ((size_t)(b * Tn + c * CL) * Hn + h) * 64;
    int tid = threadIdx.x;
    __shared__ alignas(16) __hip_bfloat16 qs[64][72];   // [t][ch]
    __shared__ alignas(16) __hip_bfloat16 ks[64][72];   // [tau][ch]
    __shared__ alignas(16) __hip_bfloat16 vsT[64][72];  // [v][tau]
    __shared__ alignas(16) __hip_bfloat16 scT[64][72];  // [v][ch]
    __shared__ alignas(16) float uni[64 * 68];          // linc, then asb
    __shared__ float wtp[4][64];
    __shared__ float diag[64];
    float (*linc)[68] = reinterpret_cast<float(*)[68]>(uni);
    __hip_bfloat16 (*asb)[72] = reinterpret_cast<__hip_bfloat16(*)[72]>(uni);
    int wave = tid >> 6, lane = tid & 63;
    {
        float acc = 0.f;
        #pragma unroll
        for (int i = 0; i < 16; i++) {
            int t = wave * 16 + i;
            acc += lw[gbase + (size_t)t * 1024 + lane];
            linc[t][lane] = acc;
        }
        wtp[wave][lane] = acc;
    }
    __syncthreads();
    {
        float off = 0.f;
        for (int g = 0; g < wave; g++) off += wtp[g][lane];
        #pragma unroll
        for (int i = 0; i < 16; i++) linc[wave * 16 + i][lane] += off;
    }
    __syncthreads();
    int t4 = tid >> 2, c0 = (tid & 3) * 16;
    float dpart = 0.f;
    #pragma unroll
    for (int i = 0; i < 4; i++) {
        int ch = c0 + i * 4;
        size_t ga = gbase + (size_t)t4 * 1024 + ch;
        ushort4 ru = *reinterpret_cast<const ushort4*>(rb + ga);
        ushort4 ku = *reinterpret_cast<const ushort4*>(kb + ga);
        ushort4 vu = *reinterpret_cast<const ushort4*>(vb + ga);
        float4 l4v = *reinterpret_cast<const float4*>(lw + ga);
        float4 u4 = *reinterpret_cast<const float4*>(tf + h * 64 + ch);
        float4 s4 = *reinterpret_cast<const float4*>(SbufT + (size_t)bid * 4096 + (size_t)t4 * 64 + ch);
        float rr[4] = {bfbits2f(ru.x), bfbits2f(ru.y), bfbits2f(ru.z), bfbits2f(ru.w)};
        float kkv[4] = {bfbits2f(ku.x), bfbits2f(ku.y), bfbits2f(ku.z), bfbits2f(ku.w)};
        float vv[4] = {bfbits2f(vu.x), bfbits2f(vu.y), bfbits2f(vu.z), bfbits2f(vu.w)};
        float lwv[4] = {l4v.x, l4v.y, l4v.z, l4v.w};
        float uu[4] = {u4.x, u4.y, u4.z, u4.w};
        float ss[4] = {s4.x, s4.y, s4.z, s4.w};
        #pragma unroll
        for (int j = 0; j < 4; j++) {
            float li = linc[t4][ch + j];
            qs[t4][ch + j] = __float2bfloat16(rr[j] * expf(li - lwv[j]));
            ks[t4][ch + j] = __float2bfloat16(kkv[j] * expf(-li));
            vsT[ch + j][t4] = __float2bfloat16(vv[j]);
            scT[t4][ch + j] = __float2bfloat16(ss[j]);   // row t4 = v
            dpart = fmaf(rr[j] * uu[j], kkv[j], dpart);
        }
    }
    dpart += __shfl_xor(dpart, 1);
    dpart += __shfl_xor(dpart, 2);
    if ((tid & 3) == 0) diag[t4] = dpart;
    __syncthreads();        // linc dead; asb may now overwrite uni
    int l15 = lane & 15, l4q = lane >> 4;
    #pragma unroll
    for (int nt = 0; nt < 4; nt++) {
        f32x4_t acc = {};
        if (nt <= wave) {
            #pragma unroll
            for (int kt = 0; kt < 2; kt++) {
                bf16x8_t a = *reinterpret_cast<const bf16x8_t*>(&qs[wave * 16 + l15][kt * 32 + l4q * 8]);
                bf16x8_t bb = *reinterpret_cast<const bf16x8_t*>(&ks[nt * 16 + l15][kt * 32 + l4q * 8]);
                acc = __builtin_amdgcn_mfma_f32_16x16x32_bf16(a, bb, acc, 0, 0, 0);
            }
        }
        #pragma unroll
        for (int q = 0; q < 4; q++) {
            int t = wave * 16 + l4q * 4 + q;
            int tau = nt * 16 + l15;
            float v = (tau < t) ? acc[q] : (tau == t ? diag[t] : 0.f);
            asb[t][tau] = __float2bfloat16(v);
        }
    }
    __syncthreads();
    #pragma unroll
    for (int nt = 0; nt < 4; nt++) {
        f32x4_t acc = {};
        int kmax = (wave >> 1) + 1;
        for (int kt = 0; kt < kmax; kt++) {
            bf16x8_t a = *reinterpret_cast<const bf16x8_t*>(&asb[wave * 16 + l15][kt * 32 + l4q * 8]);
            bf16x8_t bb = *reinterpret_cast<const bf16x8_t*>(&vsT[nt * 16 + l15][kt * 32 + l4q * 8]);
            acc = __builtin_amdgcn_mfma_f32_16x16x32_bf16(a, bb, acc, 0, 0, 0);
        }
        #pragma unroll
        for (int kt = 0; kt < 2; kt++) {
            bf16x8_t a = *reinterpret_cast<const bf16x8_t*>(&qs[wave * 16 + l15][kt * 32 + l4q * 8]);
            bf16x8_t bb = *reinterpret_cast<const bf16x8_t*>(&scT[nt * 16 + l15][kt * 32 + l4q * 8]);
            acc = __builtin_amdgcn_mfma_f32_16x16x32_bf16(a, bb, acc, 0, 0, 0);
        }
        #pragma unroll
        for (int q = 0; q < 4; q++) {
            int t = wave * 16 + l4q * 4 + q;
            y[gbase + (size_t)t * 1024 + nt * 16 + l15] = acc[q];
        }
    }
}

// ---------------------------------------------------------------------------
// GroupNorm per (bt,h) over 64 channels (after /8), *ln_w + ln_b, then *g.
// ---------------------------------------------------------------------------
__global__ __launch_bounds__(256) void gn_mul(const float* __restrict__ y,
                                              const __hip_bfloat16* __restrict__ g,
                                              const float* __restrict__ lnw,
                                              const float* __restrict__ lnb,
                                              __hip_bfloat16* __restrict__ fin) {
    int tid = threadIdx.x;
    int lane = tid & 63;
    int wv = tid >> 6;
    int grp = blockIdx.x * 4 + wv;    // bt*16 + h
    int h = grp & 15;
    size_t idx = (size_t)grp * 64 + lane;
    float val = y[idx] * 0.125f;
    float sum = val, sq = val * val;
    #pragma unroll
    for (int off = 32; off > 0; off >>= 1) {
        sum += __shfl_xor(sum, off, 64);
        sq  += __shfl_xor(sq,  off, 64);
    }
    float mu = sum * (1.f / 64.f);
    float var = sq * (1.f / 64.f) - mu * mu;
    float rs = rsqrtf(var + 1e-5f);
    float o = (val - mu) * rs * lnw[h * 64 + lane] + lnb[h * 64 + lane];
    fin[idx] = __float2bfloat16(o * __bfloat162float(g[idx]));
}

// ---------------------------------------------------------------------------
extern "C" void kernel_launch(void* const* d_in, const int* in_sizes, int n_in,
                              void* d_out, int out_size, void* d_ws, size_t ws_size,
                              hipStream_t stream) {
    (void)in_sizes; (void)n_in; (void)out_size; (void)ws_size;
    const float* x      = (const float*)d_in[0];
    const float* x_maa  = (const float*)d_in[1];
    const float* w_maa  = (const float*)d_in[2];
    const float* k_maa  = (const float*)d_in[3];
    const float* v_maa  = (const float*)d_in[4];
    const float* r_maa  = (const float*)d_in[5];
    const float* g_maa  = (const float*)d_in[6];
    const float* tm_w1  = (const float*)d_in[7];
    const float* tm_w2  = (const float*)d_in[8];
    const float* td_w1  = (const float*)d_in[9];
    const float* td_w2  = (const float*)d_in[10];
    const float* t_dec  = (const float*)d_in[11];
    const float* t_first= (const float*)d_in[12];
    const float* Wr     = (const float*)d_in[13];
    const float* Wk     = (const float*)d_in[14];
    const float* Wv     = (const float*)d_in[15];
    const float* Wg     = (const float*)d_in[16];
    const float* Wo     = (const float*)d_in[17];
    const float* ln_w   = (const float*)d_in[18];
    const float* ln_b   = (const float*)d_in[19];
    float* out = (float*)d_out;

    // Byte allocator, 256B aligned
    char* ws = (char*)d_ws;
    size_t off = 0;
    auto alloc = [&](size_t bytes) -> void* {
        void* p = ws + off;
        off = (off + bytes + 255) & ~(size_t)255;
        return p;
    };
    __hip_bfloat16* mixin = (__hip_bfloat16*)alloc(BTC * 2);  // alias: rb (bf16)
    float* mix160 = (float*)alloc((size_t)BT * 160 * 4);
    float* wxr    = (float*)alloc(BTC * 4);            // wx -> BcB -> ybuf
    __hip_bfloat16* kxb = (__hip_bfloat16*)alloc(BTC * 2);  // alias: fin
    __hip_bfloat16* vxb = (__hip_bfloat16*)alloc(BTC * 2);
    __hip_bfloat16* rxb = (__hip_bfloat16*)alloc(BTC * 2);  // rxb+gxb -> SbufT (16MB)
    __hip_bfloat16* gxb = (__hip_bfloat16*)alloc(BTC * 2);
    __hip_bfloat16* kb  = (__hip_bfloat16*)alloc(BTC * 2);
    __hip_bfloat16* vb  = (__hip_bfloat16*)alloc(BTC * 2);
    __hip_bfloat16* gb  = (__hip_bfloat16*)alloc(BTC * 2);
    float* wl1 = (float*)alloc((size_t)BT * 64 * 4);   // alias: WtB
    float* lwb = (float*)alloc(BTC * 4);
    __hip_bfloat16* WrT = (__hip_bfloat16*)alloc((size_t)Cn * Cn * 2);
    __hip_bfloat16* WkT = (__hip_bfloat16*)alloc((size_t)Cn * Cn * 2);
    __hip_bfloat16* WvT = (__hip_bfloat16*)alloc((size_t)Cn * Cn * 2);
    __hip_bfloat16* WgT = (__hip_bfloat16*)alloc((size_t)Cn * Cn * 2);
    __hip_bfloat16* WoT = (__hip_bfloat16*)alloc((size_t)Cn * Cn * 2);
    __hip_bfloat16* tmw1T = (__hip_bfloat16*)alloc((size_t)160 * Cn * 2);
    float* skpart = (float*)alloc((size_t)8 * BT * 64 * 4);    // decay split-K partials (8MB)
    float* lorapart = (float*)alloc((size_t)4 * BT * 160 * 4); // LoRA1 split-K partials (10.5MB)
    // Aliases (stream-ordered; producers complete before reuse):
    __hip_bfloat16* rb = mixin;    // r projection (mixin dead after LoRA1)
    float* BcB   = wxr;            // chunk contributions (wx dead after splitk)
    float* ybuf  = wxr;            // recurrence out (BcB dead after chunk_scan)
    float* WtB   = wl1;            // chunk decay totals (wl1 dead after decay GEMM)
    float* SbufT = (float*)rxb;    // entry states (transposed), spans rxb+gxb
    __hip_bfloat16* fin = kxb;     // gn output (kxb dead after projections)

    dim3 blk(256);
    // weight transpose+convert (one dispatch for the 5 square weights)
    transp5<<<dim3(32, 32, 5), blk, 0, stream>>>(Wr, Wk, Wv, Wg, Wo,
                                                 WrT, WkT, WvT, WgT, WoT);
    transp_bf16<<<dim3(5, 32), blk, 0, stream>>>(tm_w1, tmw1T, Cn, 160);
    // token-mix LoRA1 (bf16 MFMA split-K over 4 K-parts, 512 blocks)
    prep_mixin<<<dim3((unsigned)(BTC / 1024)), blk, 0, stream>>>(x, x_maa, mixin);
    gemm_mfma_sk<4><<<dim3(2, 64, 4), blk, 0, stream>>>(mixin, tmw1T, lorapart, BT, 160, Cn);
    splitk_reduce_tanh<4><<<dim3((BT * 160 + 255) / 256), blk, 0, stream>>>(
        lorapart, mix160, BT * 160, (size_t)BT * 160);
    deltas_mix<<<dim3(BT / 4), blk, 0, stream>>>(x, mix160, tm_w2,
                                                 w_maa, k_maa, v_maa, r_maa, g_maa,
                                                 wxr, kxb, vxb, rxb, gxb);
    // projections: ONE grouped dispatch (r,k,v,g), m-fastest grid for XCD/L2 locality
    gemm_qkvg<<<dim3(64, 8, 4), blk, 0, stream>>>(rxb, kxb, vxb, gxb,
                                                  WrT, WkT, WvT, WgT,
                                                  rb, kb, vb, gb, BT, Cn, Cn);
    // decay LoRA1 (f32 split-K, 512 blocks) + fused reduce/tanh
    gemm_f32_splitk<8><<<dim3(8, 64), blk, 0, stream>>>(wxr, td_w1, skpart, BT, 64, Cn);
    splitk_reduce_tanh<8><<<dim3(BT * 64 / 256), blk, 0, stream>>>(skpart, wl1, BT * 64,
                                                                   (size_t)BT * 64);
    // decay GEMM2 (f32, precision-sensitive)
    gemm_f32<3><<<dim3(16, 64), blk, 0, stream>>>(wl1, td_w2, lwb, BT, Cn, 64, t_dec);
    // chunked scan (MFMA)
    chunk_summary<<<dim3(Bn * Hn * NC), blk, 0, stream>>>(kb, vb, lwb, BcB, WtB);
    chunk_scan<<<dim3(Bn * Hn * 4), blk, 0, stream>>>(BcB, WtB, SbufT);
    chunk_out<<<dim3(Bn * Hn * NC), blk, 0, stream>>>(rb, kb, vb, lwb, SbufT, t_first, ybuf);
    // epilogue
    gn_mul<<<dim3(BT * Hn / 4), blk, 0, stream>>>(ybuf, gb, ln_w, ln_b, fin);
    gemm_mfma_gl<<<dim3(64, 8), blk, 0, stream>>>(fin, WoT, out, BT, Cn, Cn);
}

// Round 13
// 211.649 us; speedup vs baseline: 1.2087x; 1.0208x over previous
//
#include <hip/hip_runtime.h>
#include <hip/hip_bf16.h>
#include <math.h>
#include <stdint.h>

// Problem constants
constexpr int Bn = 4, Tn = 1024, Cn = 1024, Hn = 16;
constexpr int BT = Bn * Tn;                 // 4096
constexpr long long BTC = (long long)BT * Cn;  // 4M elements
constexpr int CL = 64;                      // chunk length
constexpr int NC = Tn / CL;                 // 16 chunks

typedef __bf16 bf16x8_t __attribute__((ext_vector_type(8)));
typedef float f32x4_t __attribute__((ext_vector_type(4)));
typedef unsigned short us8_t __attribute__((ext_vector_type(8)));

__device__ __forceinline__ unsigned short f2bf_bits(float v) {
    __hip_bfloat16 h = __float2bfloat16(v);
    return *reinterpret_cast<unsigned short*>(&h);
}
__device__ __forceinline__ float bfbits2f(unsigned short u) {
    unsigned int x = (unsigned int)u << 16;
    return __uint_as_float(x);
}

// Direct global->LDS 16B/lane (wave-uniform LDS base + lane*16). CK-style casts.
__device__ __forceinline__ void gload16(const void* g, void* l) {
    auto const* gp = reinterpret_cast<const unsigned int __attribute__((address_space(1)))*>(
        reinterpret_cast<uintptr_t>(g));
    auto* lp = reinterpret_cast<unsigned int __attribute__((address_space(3)))*>(
        reinterpret_cast<uintptr_t>(l));
    __builtin_amdgcn_global_load_lds(gp, lp, 16, 0, 0);
}

// ---------------------------------------------------------------------------
// mix input for the token-mix LoRA (x4 vectorized)
// ---------------------------------------------------------------------------
__global__ __launch_bounds__(256) void prep_mixin(const float* __restrict__ x,
                                                  const float* __restrict__ x_maa,
                                                  __hip_bfloat16* __restrict__ out) {
    long long q = (long long)blockIdx.x * 256 + threadIdx.x;   // quad index
    if (q * 4 >= BTC) return;
    long long idx = q * 4;
    int c = (int)(idx & (Cn - 1));
    long long bt = idx >> 10;
    int t = (int)(bt & (Tn - 1));
    float4 xv = *reinterpret_cast<const float4*>(x + idx);
    float4 xp = (t > 0) ? *reinterpret_cast<const float4*>(x + idx - Cn)
                        : make_float4(0.f, 0.f, 0.f, 0.f);
    float4 ma = *reinterpret_cast<const float4*>(x_maa + c);
    ushort4 o;
    o.x = f2bf_bits(xv.x + (xp.x - xv.x) * ma.x);
    o.y = f2bf_bits(xv.y + (xp.y - xv.y) * ma.y);
    o.z = f2bf_bits(xv.z + (xp.z - xv.z) * ma.z);
    o.w = f2bf_bits(xv.w + (xp.w - xv.w) * ma.w);
    *reinterpret_cast<ushort4*>(out + idx) = o;
}

// ---------------------------------------------------------------------------
// Transpose + convert, 5 square weights in one dispatch (z selects matrix).
// ---------------------------------------------------------------------------
__global__ __launch_bounds__(256) void transp5(const float* __restrict__ W0,
                                               const float* __restrict__ W1,
                                               const float* __restrict__ W2,
                                               const float* __restrict__ W3,
                                               const float* __restrict__ W4,
                                               __hip_bfloat16* __restrict__ T0,
                                               __hip_bfloat16* __restrict__ T1,
                                               __hip_bfloat16* __restrict__ T2,
                                               __hip_bfloat16* __restrict__ T3,
                                               __hip_bfloat16* __restrict__ T4) {
    int z = blockIdx.z;
    const float* W = (z == 0) ? W0 : (z == 1) ? W1 : (z == 2) ? W2 : (z == 3) ? W3 : W4;
    __hip_bfloat16* Wt = (z == 0) ? T0 : (z == 1) ? T1 : (z == 2) ? T2 : (z == 3) ? T3 : T4;
    __shared__ float tile[32][33];
    int c0 = blockIdx.x * 32, r0 = blockIdx.y * 32;
    int tx = threadIdx.x & 31, ty = threadIdx.x >> 5;
    #pragma unroll
    for (int i = 0; i < 4; i++)
        tile[ty + 8 * i][tx] = W[(size_t)(r0 + ty + 8 * i) * Cn + c0 + tx];
    __syncthreads();
    #pragma unroll
    for (int i = 0; i < 4; i++)
        Wt[(size_t)(c0 + ty + 8 * i) * Cn + r0 + tx] = __float2bfloat16(tile[tx][ty + 8 * i]);
}

// Generic single transpose: W [R][Cc] f32 -> Wt [Cc][R] bf16
__global__ __launch_bounds__(256) void transp_bf16(const float* __restrict__ W,
                                                   __hip_bfloat16* __restrict__ Wt,
                                                   int R, int Cc) {
    __shared__ float tile[32][33];
    int c0 = blockIdx.x * 32, r0 = blockIdx.y * 32;
    int tx = threadIdx.x & 31, ty = threadIdx.x >> 5;
    #pragma unroll
    for (int i = 0; i < 4; i++)
        tile[ty + 8 * i][tx] = W[(size_t)(r0 + ty + 8 * i) * Cc + c0 + tx];
    __syncthreads();
    #pragma unroll
    for (int i = 0; i < 4; i++)
        Wt[(size_t)(c0 + ty + 8 * i) * R + r0 + tx] = __float2bfloat16(tile[tx][ty + 8 * i]);
}

// ---------------------------------------------------------------------------
// f32 tiled GEMM (decay LoRA GEMM2, precision-sensitive): C = A[M,K]@B[K,N].
// EPI: 3 logdecay (-exp(extra[col]+acc))
// ---------------------------------------------------------------------------
template <int EPI>
__global__ __launch_bounds__(256) void gemm_f32(const float* __restrict__ A,
                                                const float* __restrict__ Bm,
                                                float* __restrict__ C,
                                                int M, int N, int K,
                                                const float* __restrict__ extra) {
    __shared__ float As[16][64];
    __shared__ float Bs[16][64];
    int tid = threadIdx.x;
    int m0 = blockIdx.y * 64, n0 = blockIdx.x * 64;
    int tx = tid & 15, ty = tid >> 4;
    int ar = tid >> 2, ac = (tid & 3) * 4;
    int br = tid >> 4, bc = (tid & 15) * 4;
    float acc[4][4] = {};

    for (int k0 = 0; k0 < K; k0 += 16) {
        const float* ap = A + (size_t)(m0 + ar) * K + k0 + ac;
        float4 av = *reinterpret_cast<const float4*>(ap);
        As[ac + 0][ar] = av.x; As[ac + 1][ar] = av.y;
        As[ac + 2][ar] = av.z; As[ac + 3][ar] = av.w;
        float4 bv = *reinterpret_cast<const float4*>(Bm + (size_t)(k0 + br) * N + n0 + bc);
        *reinterpret_cast<float4*>(&Bs[br][bc]) = bv;
        __syncthreads();
        #pragma unroll
        for (int kk = 0; kk < 16; kk++) {
            float4 a4 = *reinterpret_cast<const float4*>(&As[kk][ty * 4]);
            float4 b4 = *reinterpret_cast<const float4*>(&Bs[kk][tx * 4]);
            float aa[4] = {a4.x, a4.y, a4.z, a4.w};
            float bb[4] = {b4.x, b4.y, b4.z, b4.w};
            #pragma unroll
            for (int i = 0; i < 4; i++)
                #pragma unroll
                for (int j = 0; j < 4; j++)
                    acc[i][j] = fmaf(aa[i], bb[j], acc[i][j]);
        }
        __syncthreads();
    }

    #pragma unroll
    for (int i = 0; i < 4; i++) {
        int row = m0 + ty * 4 + i;
        #pragma unroll
        for (int j = 0; j < 4; j++) {
            int col = n0 + tx * 4 + j;
            float v = acc[i][j];
            if (EPI == 3) v = -expf(extra[col] + v);
            C[(size_t)row * N + col] = v;
        }
    }
}

// ---------------------------------------------------------------------------
// Split-K f32 GEMM for the decay LoRA1 ([4096,1024]@[1024,64], N==64).
// ---------------------------------------------------------------------------
template <int KS>
__global__ __launch_bounds__(256) void gemm_f32_splitk(const float* __restrict__ A,
                                                       const float* __restrict__ Bm,
                                                       float* __restrict__ part,
                                                       int M, int N, int K) {
    __shared__ float As[16][64];
    __shared__ float Bs[16][64];
    int tid = threadIdx.x;
    int kp = blockIdx.x;
    int m0 = blockIdx.y * 64;
    int kbeg = kp * (K / KS), kend = kbeg + K / KS;
    int tx = tid & 15, ty = tid >> 4;
    int ar = tid >> 2, ac = (tid & 3) * 4;
    int br = tid >> 4, bc = (tid & 15) * 4;
    float acc[4][4] = {};

    for (int k0 = kbeg; k0 < kend; k0 += 16) {
        float4 av = *reinterpret_cast<const float4*>(A + (size_t)(m0 + ar) * K + k0 + ac);
        As[ac + 0][ar] = av.x; As[ac + 1][ar] = av.y;
        As[ac + 2][ar] = av.z; As[ac + 3][ar] = av.w;
        *reinterpret_cast<float4*>(&Bs[br][bc]) =
            *reinterpret_cast<const float4*>(Bm + (size_t)(k0 + br) * N + bc);
        __syncthreads();
        #pragma unroll
        for (int kk = 0; kk < 16; kk++) {
            float4 a4 = *reinterpret_cast<const float4*>(&As[kk][ty * 4]);
            float4 b4 = *reinterpret_cast<const float4*>(&Bs[kk][tx * 4]);
            float aa[4] = {a4.x, a4.y, a4.z, a4.w};
            float bb[4] = {b4.x, b4.y, b4.z, b4.w};
            #pragma unroll
            for (int i = 0; i < 4; i++)
                #pragma unroll
                for (int j = 0; j < 4; j++)
                    acc[i][j] = fmaf(aa[i], bb[j], acc[i][j]);
        }
        __syncthreads();
    }
    #pragma unroll
    for (int i = 0; i < 4; i++) {
        int row = m0 + ty * 4 + i;
        #pragma unroll
        for (int j = 0; j < 4; j++)
            part[((size_t)kp * M + row) * N + tx * 4 + j] = acc[i][j];
    }
}

// Reduce KS partials + tanh -> f32
template <int KS>
__global__ __launch_bounds__(256) void splitk_reduce_tanh(const float* __restrict__ part,
                                                          float* __restrict__ outp,
                                                          int total, size_t stride) {
    int i = blockIdx.x * 256 + threadIdx.x;
    if (i >= total) return;
    float s = 0.f;
    #pragma unroll
    for (int kp = 0; kp < KS; kp++) s += part[kp * stride + i];
    outp[i] = tanhf(s);
}

// Reduce KS partials + tanh -> bf16
template <int KS>
__global__ __launch_bounds__(256) void splitk_reduce_tanh_bf(const float* __restrict__ part,
                                                             __hip_bfloat16* __restrict__ outp,
                                                             int total, size_t stride) {
    int i = blockIdx.x * 256 + threadIdx.x;
    if (i >= total) return;
    float s = 0.f;
    #pragma unroll
    for (int kp = 0; kp < KS; kp++) s += part[kp * stride + i];
    outp[i] = __float2bfloat16(tanhf(s));
}

// ---------------------------------------------------------------------------
// Split-K bf16 MFMA GEMM for token-mix LoRA1 ([4096,1024]@[1024,160]).
// ---------------------------------------------------------------------------
template <int KS>
__global__ __launch_bounds__(256) void gemm_mfma_sk(const __hip_bfloat16* __restrict__ A,
                                                    const __hip_bfloat16* __restrict__ Bt,
                                                    float* __restrict__ part,
                                                    int M, int N, int K) {
    __shared__ alignas(16) unsigned short As[64 * 64];
    __shared__ alignas(16) unsigned short Bs[128 * 64];
    int tid = threadIdx.x;
    int m0 = blockIdx.y * 64, n0 = blockIdx.x * 128;
    int kp = blockIdx.z;
    int kbeg = kp * (K / KS), kend = kbeg + K / KS;
    int wave = tid >> 6, lane = tid & 63;
    int wm = (wave & 1) * 32, wn = (wave >> 1) * 64;
    int l15 = lane & 15, l4 = lane >> 4;
    f32x4_t acc[2][4] = {};

    for (int k0 = kbeg; k0 < kend; k0 += 64) {
        #pragma unroll
        for (int p = 0; p < 2; p++) {
            int cch = tid + p * 256;
            int row = cch >> 3, slot = cch & 7;
            int s2 = slot ^ (row & 7);
            *reinterpret_cast<us8_t*>(&As[row * 64 + s2 * 8]) =
                *reinterpret_cast<const us8_t*>(&A[(size_t)(m0 + row) * K + k0 + slot * 8]);
        }
        #pragma unroll
        for (int p = 0; p < 4; p++) {
            int cch = tid + p * 256;
            int row = cch >> 3, slot = cch & 7;
            int s2 = slot ^ (row & 7);
            int rowg = n0 + row; if (rowg > N - 1) rowg = N - 1;  // clamp
            *reinterpret_cast<us8_t*>(&Bs[row * 64 + s2 * 8]) =
                *reinterpret_cast<const us8_t*>(&Bt[(size_t)rowg * K + k0 + slot * 8]);
        }
        __syncthreads();
        #pragma unroll
        for (int kw = 0; kw < 2; kw++) {
            int slot = kw * 4 + l4;
            bf16x8_t af[2], bfr[4];
            #pragma unroll
            for (int f = 0; f < 2; f++) {
                int ar = wm + f * 16 + l15;
                af[f] = *reinterpret_cast<const bf16x8_t*>(&As[ar * 64 + (slot ^ (ar & 7)) * 8]);
            }
            #pragma unroll
            for (int f = 0; f < 4; f++) {
                int br = wn + f * 16 + l15;
                bfr[f] = *reinterpret_cast<const bf16x8_t*>(&Bs[br * 64 + (slot ^ (br & 7)) * 8]);
            }
            #pragma unroll
            for (int i = 0; i < 2; i++)
                #pragma unroll
                for (int j = 0; j < 4; j++)
                    acc[i][j] = __builtin_amdgcn_mfma_f32_16x16x32_bf16(af[i], bfr[j], acc[i][j], 0, 0, 0);
        }
        __syncthreads();
    }

    #pragma unroll
    for (int i = 0; i < 2; i++) {
        int rbase = m0 + wm + i * 16 + l4 * 4;
        #pragma unroll
        for (int j = 0; j < 4; j++) {
            int col = n0 + wn + j * 16 + l15;
            if (col < N) {
                #pragma unroll
                for (int q = 0; q < 4; q++)
                    part[((size_t)kp * M + rbase + q) * N + col] = acc[i][j][q];
            }
        }
    }
}

// ---------------------------------------------------------------------------
// Deltas GEMM (batched over f=blockIdx.z): D_f = mix160b[:, f*32:(f+1)*32]
//   @ w2T[:, f*32:(f+1)*32]^T.  64x128 tile, K=32 (8 MFMAs), gload staging.
// A: [4096][160] bf16, B: w2T [1024][160] bf16, D: [5][4096][1024] bf16.
// ---------------------------------------------------------------------------
__global__ __launch_bounds__(256) void dmix_gemm(const __hip_bfloat16* __restrict__ A,
                                                 const __hip_bfloat16* __restrict__ W2T,
                                                 __hip_bfloat16* __restrict__ D) {
    __shared__ alignas(16) unsigned short As[64 * 32];
    __shared__ alignas(16) unsigned short Bs[128 * 32];
    int tid = threadIdx.x;
    int m0 = blockIdx.x * 64, n0 = blockIdx.y * 128;   // m fastest -> XCD=m%8
    int f  = blockIdx.z;
    int wave = tid >> 6, lane = tid & 63;
    int wm = (wave & 1) * 32, wn = (wave >> 1) * 64;
    int l15 = lane & 15, l4 = lane >> 4;
    int lrow2 = lane >> 2, ls = lane & 3;   // 16 rows x 4 slots per gload
    f32x4_t acc[2][4] = {};

    // stage A rows [wave*16, wave*16+16)
    {
        int row = wave * 16 + lrow2;
        int gs = ls ^ (row & 3);
        gload16(&A[(size_t)(m0 + row) * 160 + f * 32 + gs * 8], &As[(wave * 16) * 32]);
    }
    // stage B rows [wave*32, wave*32+32) in 2 calls of 16 rows
    #pragma unroll
    for (int ci = 0; ci < 2; ci++) {
        int r0 = wave * 32 + ci * 16;
        int row = r0 + lrow2;
        int gs = ls ^ (row & 3);
        gload16(&W2T[(size_t)(n0 + row) * 160 + f * 32 + gs * 8], &Bs[r0 * 32]);
    }
    __syncthreads();
    bf16x8_t af[2], bfr[4];
    #pragma unroll
    for (int i = 0; i < 2; i++) {
        int ar = wm + i * 16 + l15;
        af[i] = *reinterpret_cast<const bf16x8_t*>(&As[ar * 32 + ((l4 ^ (ar & 3)) * 8)]);
    }
    #pragma unroll
    for (int j = 0; j < 4; j++) {
        int br = wn + j * 16 + l15;
        bfr[j] = *reinterpret_cast<const bf16x8_t*>(&Bs[br * 32 + ((l4 ^ (br & 3)) * 8)]);
    }
    #pragma unroll
    for (int i = 0; i < 2; i++)
        #pragma unroll
        for (int j = 0; j < 4; j++)
            acc[i][j] = __builtin_amdgcn_mfma_f32_16x16x32_bf16(af[i], bfr[j], acc[i][j], 0, 0, 0);

    __hip_bfloat16* Df = D + (size_t)f * BTC;
    #pragma unroll
    for (int i = 0; i < 2; i++) {
        int rbase = m0 + wm + i * 16 + l4 * 4;
        #pragma unroll
        for (int j = 0; j < 4; j++) {
            int col = n0 + wn + j * 16 + l15;
            #pragma unroll
            for (int q = 0; q < 4; q++)
                Df[(size_t)(rbase + q) * Cn + col] = __float2bfloat16(acc[i][j][q]);
        }
    }
}

// ---------------------------------------------------------------------------
// Fuse deltas: out_f = x + sx*(maa_f + D_f). Vectorized x4. 1:1 mapping.
// ---------------------------------------------------------------------------
__global__ __launch_bounds__(256) void dmix_fuse(const float* __restrict__ x,
                                                 const __hip_bfloat16* __restrict__ D,
                                                 const float* __restrict__ wmaa,
                                                 const float* __restrict__ kmaa,
                                                 const float* __restrict__ vmaa,
                                                 const float* __restrict__ rmaa,
                                                 const float* __restrict__ gmaa,
                                                 float* __restrict__ wx,
                                                 __hip_bfloat16* __restrict__ kxb,
                                                 __hip_bfloat16* __restrict__ vxb,
                                                 __hip_bfloat16* __restrict__ rxb,
                                                 __hip_bfloat16* __restrict__ gxb) {
    long long q = (long long)blockIdx.x * 256 + threadIdx.x;
    if (q * 4 >= BTC) return;
    long long idx = q * 4;
    int c = (int)(idx & (Cn - 1));
    int t = (int)((idx >> 10) & (Tn - 1));
    float4 xv = *reinterpret_cast<const float4*>(x + idx);
    float4 xp = (t > 0) ? *reinterpret_cast<const float4*>(x + idx - Cn)
                        : make_float4(0.f, 0.f, 0.f, 0.f);
    float sx[4] = {xp.x - xv.x, xp.y - xv.y, xp.z - xv.z, xp.w - xv.w};
    float xvv[4] = {xv.x, xv.y, xv.z, xv.w};
    #pragma unroll
    for (int f = 0; f < 5; f++) {
        const float* maa = (f == 0) ? wmaa : (f == 1) ? kmaa : (f == 2) ? vmaa
                         : (f == 3) ? rmaa : gmaa;
        float4 m4 = *reinterpret_cast<const float4*>(maa + c);
        float mm[4] = {m4.x, m4.y, m4.z, m4.w};
        ushort4 d4 = *reinterpret_cast<const ushort4*>(D + (size_t)f * BTC + idx);
        float dd[4] = {bfbits2f(d4.x), bfbits2f(d4.y), bfbits2f(d4.z), bfbits2f(d4.w)};
        float val[4];
        #pragma unroll
        for (int j = 0; j < 4; j++) val[j] = xvv[j] + sx[j] * (mm[j] + dd[j]);
        if (f == 0) {
            *reinterpret_cast<float4*>(wx + idx) = make_float4(val[0], val[1], val[2], val[3]);
        } else {
            ushort4 o;
            o.x = f2bf_bits(val[0]); o.y = f2bf_bits(val[1]);
            o.z = f2bf_bits(val[2]); o.w = f2bf_bits(val[3]);
            __hip_bfloat16* dst = (f == 1) ? kxb : (f == 2) ? vxb : (f == 3) ? rxb : gxb;
            *reinterpret_cast<ushort4*>(dst + idx) = o;
        }
    }
}

// ---------------------------------------------------------------------------
// GROUPED bf16 MFMA GEMM: 4 projections (r,k,v,g) in ONE dispatch.
// 64x128 tile; m-fastest grid for XCD/L2 locality. Outputs bf16; z==3 silu.
// ---------------------------------------------------------------------------
__global__ __launch_bounds__(256) void gemm_qkvg(const __hip_bfloat16* __restrict__ A0,
                                                 const __hip_bfloat16* __restrict__ A1,
                                                 const __hip_bfloat16* __restrict__ A2,
                                                 const __hip_bfloat16* __restrict__ A3,
                                                 const __hip_bfloat16* __restrict__ B0,
                                                 const __hip_bfloat16* __restrict__ B1,
                                                 const __hip_bfloat16* __restrict__ B2,
                                                 const __hip_bfloat16* __restrict__ B3,
                                                 __hip_bfloat16* __restrict__ C0,
                                                 __hip_bfloat16* __restrict__ C1,
                                                 __hip_bfloat16* __restrict__ C2,
                                                 __hip_bfloat16* __restrict__ C3,
                                                 int M, int N, int K) {
    int g = blockIdx.z;
    const __hip_bfloat16* A  = (g == 0) ? A0 : (g == 1) ? A1 : (g == 2) ? A2 : A3;
    const __hip_bfloat16* Bt = (g == 0) ? B0 : (g == 1) ? B1 : (g == 2) ? B2 : B3;
    __hip_bfloat16* Co = (g == 0) ? C0 : (g == 1) ? C1 : (g == 2) ? C2 : C3;
    __shared__ alignas(16) unsigned short As[64 * 64];
    __shared__ alignas(16) unsigned short Bs[128 * 64];
    int tid = threadIdx.x;
    int m0 = blockIdx.x * 64, n0 = blockIdx.y * 128;   // m fastest -> XCD=m%8
    int wave = tid >> 6, lane = tid & 63;
    int wm = (wave & 1) * 32, wn = (wave >> 1) * 64;
    int l15 = lane & 15, l4 = lane >> 4;
    int lrow = lane >> 3, ls2 = lane & 7;
    f32x4_t acc[2][4] = {};

    for (int k0 = 0; k0 < K; k0 += 64) {
        #pragma unroll
        for (int ci = 0; ci < 2; ci++) {
            int r0 = wave * 16 + ci * 8;
            int row = r0 + lrow;
            int gs = ls2 ^ (row & 7);
            gload16(&A[(size_t)(m0 + row) * K + k0 + gs * 8], &As[r0 * 64]);
        }
        #pragma unroll
        for (int ci = 0; ci < 4; ci++) {
            int r0 = wave * 32 + ci * 8;
            int row = r0 + lrow;
            int gs = ls2 ^ (row & 7);
            gload16(&Bt[(size_t)(n0 + row) * K + k0 + gs * 8], &Bs[r0 * 64]);
        }
        __syncthreads();
        #pragma unroll
        for (int kw = 0; kw < 2; kw++) {
            int slot = kw * 4 + l4;
            bf16x8_t af[2], bfr[4];
            #pragma unroll
            for (int f = 0; f < 2; f++) {
                int ar = wm + f * 16 + l15;
                af[f] = *reinterpret_cast<const bf16x8_t*>(&As[ar * 64 + (slot ^ (ar & 7)) * 8]);
            }
            #pragma unroll
            for (int f = 0; f < 4; f++) {
                int br = wn + f * 16 + l15;
                bfr[f] = *reinterpret_cast<const bf16x8_t*>(&Bs[br * 64 + (slot ^ (br & 7)) * 8]);
            }
            #pragma unroll
            for (int i = 0; i < 2; i++)
                #pragma unroll
                for (int j = 0; j < 4; j++)
                    acc[i][j] = __builtin_amdgcn_mfma_f32_16x16x32_bf16(af[i], bfr[j], acc[i][j], 0, 0, 0);
        }
        __syncthreads();
    }

    #pragma unroll
    for (int i = 0; i < 2; i++) {
        int rbase = m0 + wm + i * 16 + l4 * 4;
        #pragma unroll
        for (int j = 0; j < 4; j++) {
            int col = n0 + wn + j * 16 + l15;
            #pragma unroll
            for (int q = 0; q < 4; q++) {
                float v = acc[i][j][q];
                if (g == 3) v = v / (1.f + expf(-v));
                Co[(size_t)(rbase + q) * N + col] = __float2bfloat16(v);
            }
        }
    }
}

// Wo projection (single, gl-staged, 64x128 tile, m-fastest grid), f32 out
__global__ __launch_bounds__(256) void gemm_mfma_gl(const __hip_bfloat16* __restrict__ A,
                                                    const __hip_bfloat16* __restrict__ Bt,
                                                    float* __restrict__ Cout,
                                                    int M, int N, int K) {
    __shared__ alignas(16) unsigned short As[64 * 64];
    __shared__ alignas(16) unsigned short Bs[128 * 64];
    int tid = threadIdx.x;
    int m0 = blockIdx.x * 64, n0 = blockIdx.y * 128;   // m fastest -> XCD=m%8
    int wave = tid >> 6, lane = tid & 63;
    int wm = (wave & 1) * 32, wn = (wave >> 1) * 64;
    int l15 = lane & 15, l4 = lane >> 4;
    int lrow = lane >> 3, ls2 = lane & 7;
    f32x4_t acc[2][4] = {};

    for (int k0 = 0; k0 < K; k0 += 64) {
        #pragma unroll
        for (int ci = 0; ci < 2; ci++) {
            int r0 = wave * 16 + ci * 8;
            int row = r0 + lrow;
            int gs = ls2 ^ (row & 7);
            gload16(&A[(size_t)(m0 + row) * K + k0 + gs * 8], &As[r0 * 64]);
        }
        #pragma unroll
        for (int ci = 0; ci < 4; ci++) {
            int r0 = wave * 32 + ci * 8;
            int row = r0 + lrow;
            int gs = ls2 ^ (row & 7);
            gload16(&Bt[(size_t)(n0 + row) * K + k0 + gs * 8], &Bs[r0 * 64]);
        }
        __syncthreads();
        #pragma unroll
        for (int kw = 0; kw < 2; kw++) {
            int slot = kw * 4 + l4;
            bf16x8_t af[2], bfr[4];
            #pragma unroll
            for (int f = 0; f < 2; f++) {
                int ar = wm + f * 16 + l15;
                af[f] = *reinterpret_cast<const bf16x8_t*>(&As[ar * 64 + (slot ^ (ar & 7)) * 8]);
            }
            #pragma unroll
            for (int f = 0; f < 4; f++) {
                int br = wn + f * 16 + l15;
                bfr[f] = *reinterpret_cast<const bf16x8_t*>(&Bs[br * 64 + (slot ^ (br & 7)) * 8]);
            }
            #pragma unroll
            for (int i = 0; i < 2; i++)
                #pragma unroll
                for (int j = 0; j < 4; j++)
                    acc[i][j] = __builtin_amdgcn_mfma_f32_16x16x32_bf16(af[i], bfr[j], acc[i][j], 0, 0, 0);
        }
        __syncthreads();
    }

    #pragma unroll
    for (int i = 0; i < 2; i++) {
        int rbase = m0 + wm + i * 16 + l4 * 4;
        #pragma unroll
        for (int j = 0; j < 4; j++) {
            int col = n0 + wn + j * 16 + l15;
            #pragma unroll
            for (int q = 0; q < 4; q++)
                Cout[(size_t)(rbase + q) * N + col] = acc[i][j][q];
        }
    }
}

// ---------------------------------------------------------------------------
// Chunked WKV stage A (MFMA): per (b,h,chunk). k/v inputs bf16.
// ---------------------------------------------------------------------------
__global__ __launch_bounds__(256) void chunk_summary(const __hip_bfloat16* __restrict__ kb,
                                                     const __hip_bfloat16* __restrict__ vb,
                                                     const float* __restrict__ lw,
                                                     float* __restrict__ Bc,
                                                     float* __restrict__ Wtot) {
    int bid = blockIdx.x;
    int c = bid & 15, h = (bid >> 4) & 15, b = bid >> 8;
    size_t gbase = ((size_t)(b * Tn + c * CL) * Hn + h) * 64;
    int tid = threadIdx.x;
    __shared__ float linc[64][68];
    __shared__ float wtp[4][64];
    __shared__ alignas(16) __hip_bfloat16 kdT[64][72];  // [ch][tau]
    __shared__ alignas(16) __hip_bfloat16 vsT[64][72];  // [v][tau]
    int wave = tid >> 6, lane = tid & 63;
    {
        float acc = 0.f;
        #pragma unroll
        for (int i = 0; i < 16; i++) {
            int t = wave * 16 + i;
            acc += lw[gbase + (size_t)t * 1024 + lane];
            linc[t][lane] = acc;
        }
        wtp[wave][lane] = acc;
    }
    __syncthreads();
    {
        float off = 0.f;
        for (int g = 0; g < wave; g++) off += wtp[g][lane];
        #pragma unroll
        for (int i = 0; i < 16; i++) linc[wave * 16 + i][lane] += off;
    }
    __syncthreads();
    int t4 = tid >> 2, c0 = (tid & 3) * 16;
    #pragma unroll
    for (int i = 0; i < 4; i++) {
        int ch = c0 + i * 4;
        size_t ga = gbase + (size_t)t4 * 1024 + ch;
        ushort4 ku = *reinterpret_cast<const ushort4*>(kb + ga);
        ushort4 vu = *reinterpret_cast<const ushort4*>(vb + ga);
        float kk[4] = {bfbits2f(ku.x), bfbits2f(ku.y), bfbits2f(ku.z), bfbits2f(ku.w)};
        float vv[4] = {bfbits2f(vu.x), bfbits2f(vu.y), bfbits2f(vu.z), bfbits2f(vu.w)};
        #pragma unroll
        for (int j = 0; j < 4; j++) {
            float li = linc[t4][ch + j];
            float lend = linc[63][ch + j];
            kdT[ch + j][t4] = __float2bfloat16(kk[j] * expf(lend - li));
            vsT[ch + j][t4] = __float2bfloat16(vv[j]);
        }
    }
    if (tid < 64) Wtot[(size_t)bid * 64 + tid] = expf(linc[63][tid]);
    __syncthreads();
    int l15 = lane & 15, l4q = lane >> 4;
    #pragma unroll
    for (int nt = 0; nt < 4; nt++) {
        f32x4_t acc = {};
        #pragma unroll
        for (int kt = 0; kt < 2; kt++) {
            bf16x8_t a = *reinterpret_cast<const bf16x8_t*>(&kdT[wave * 16 + l15][kt * 32 + l4q * 8]);
            bf16x8_t bb = *reinterpret_cast<const bf16x8_t*>(&vsT[nt * 16 + l15][kt * 32 + l4q * 8]);
            acc = __builtin_amdgcn_mfma_f32_16x16x32_bf16(a, bb, acc, 0, 0, 0);
        }
        #pragma unroll
        for (int q = 0; q < 4; q++) {
            int krow = wave * 16 + l4q * 4 + q;
            Bc[(size_t)bid * 4096 + (size_t)krow * 64 + nt * 16 + l15] = acc[q];
        }
    }
}

// ---------------------------------------------------------------------------
// Stage B: sequential scan over NC=16 chunk states; TRANSPOSED entry states.
// ---------------------------------------------------------------------------
__global__ __launch_bounds__(256) void chunk_scan(const float* __restrict__ Bc,
                                                  const float* __restrict__ Wtot,
                                                  float* __restrict__ SbufT) {
    int bid = blockIdx.x;
    int bh = bid >> 2, vg = bid & 3;
    int kk = threadIdx.x >> 2;
    int v = vg * 16 + (threadIdx.x & 3) * 4;
    float4 S = make_float4(0.f, 0.f, 0.f, 0.f);
    for (int c = 0; c < NC; c++) {
        size_t base = (size_t)(bh * NC + c) * 4096;
        SbufT[base + (size_t)(v + 0) * 64 + kk] = S.x;
        SbufT[base + (size_t)(v + 1) * 64 + kk] = S.y;
        SbufT[base + (size_t)(v + 2) * 64 + kk] = S.z;
        SbufT[base + (size_t)(v + 3) * 64 + kk] = S.w;
        float wt = Wtot[(size_t)(bh * NC + c) * 64 + kk];
        float4 b4 = *reinterpret_cast<const float4*>(Bc + base + (size_t)kk * 64 + v);
        S.x = fmaf(wt, S.x, b4.x);
        S.y = fmaf(wt, S.y, b4.y);
        S.z = fmaf(wt, S.z, b4.z);
        S.w = fmaf(wt, S.w, b4.w);
    }
}

// ---------------------------------------------------------------------------
// Stage C (MFMA): Y = mask(qs@ks^T, diag) @ V + qs @ Sc. r/k/v inputs bf16.
// ---------------------------------------------------------------------------
__global__ __launch_bounds__(256) void chunk_out(const __hip_bfloat16* __restrict__ rb,
                                                 const __hip_bfloat16* __restrict__ kb,
                                                 const __hip_bfloat16* __restrict__ vb,
                                                 const float* __restrict__ lw,
                                                 const float* __restrict__ SbufT,
                                                 const float* __restrict__ tf,
                                                 float* __restrict__ y) {
    int bid = blockIdx.x;
    int c = bid & 15, h = (bid >> 4) & 15, b = bid >> 8;
    size_t gbase = ((size_t)(b * Tn + c * CL) * Hn + h) * 64;
    int tid = threadIdx.x;
    __shared__ alignas(16) __hip_bfloat16 qs[64][72];   // [t][ch]
    __shared__ alignas(16) __hip_bfloat16 ks[64][72];   // [tau][ch]
    __shared__ alignas(16) __hip_bfloat16 vsT[64][72];  // [v][tau]
    __shared__ alignas(16) __hip_bfloat16 scT[64][72];  // [v][ch]
    __shared__ alignas(16) float uni[64 * 68];          // linc, then asb
    __shared__ float wtp[4][64];
    __shared__ float diag[64];
    float (*linc)[68] = reinterpret_cast<float(*)[68]>(uni);
    __hip_bfloat16 (*asb)[72] = reinterpret_cast<__hip_bfloat16(*)[72]>(uni);
    int wave = tid >> 6, lane = tid & 63;
    {
        float acc = 0.f;
        #pragma unroll
        for (int i = 0; i < 16; i++) {
            int t = wave * 16 + i;
            acc += lw[gbase + (size_t)t * 1024 + lane];
            linc[t][lane] = acc;
        }
        wtp[wave][lane] = acc;
    }
    __syncthreads();
    {
        float off = 0.f;
        for (int g = 0; g < wave; g++) off += wtp[g][lane];
        #pragma unroll
        for (int i = 0; i < 16; i++) linc[wave * 16 + i][lane] += off;
    }
    __syncthreads();
    int t4 = tid >> 2, c0 = (tid & 3) * 16;
    float dpart = 0.f;
    #pragma unroll
    for (int i = 0; i < 4; i++) {
        int ch = c0 + i * 4;
        size_t ga = gbase + (size_t)t4 * 1024 + ch;
        ushort4 ru = *reinterpret_cast<const ushort4*>(rb + ga);
        ushort4 ku = *reinterpret_cast<const ushort4*>(kb + ga);
        ushort4 vu = *reinterpret_cast<const ushort4*>(vb + ga);
        float4 l4v = *reinterpret_cast<const float4*>(lw + ga);
        float4 u4 = *reinterpret_cast<const float4*>(tf + h * 64 + ch);
        float4 s4 = *reinterpret_cast<const float4*>(SbufT + (size_t)bid * 4096 + (size_t)t4 * 64 + ch);
        float rr[4] = {bfbits2f(ru.x), bfbits2f(ru.y), bfbits2f(ru.z), bfbits2f(ru.w)};
        float kkv[4] = {bfbits2f(ku.x), bfbits2f(ku.y), bfbits2f(ku.z), bfbits2f(ku.w)};
        float vv[4] = {bfbits2f(vu.x), bfbits2f(vu.y), bfbits2f(vu.z), bfbits2f(vu.w)};
        float lwv[4] = {l4v.x, l4v.y, l4v.z, l4v.w};
        float uu[4] = {u4.x, u4.y, u4.z, u4.w};
        float ss[4] = {s4.x, s4.y, s4.z, s4.w};
        #pragma unroll
        for (int j = 0; j < 4; j++) {
            float li = linc[t4][ch + j];
            qs[t4][ch + j] = __float2bfloat16(rr[j] * expf(li - lwv[j]));
            ks[t4][ch + j] = __float2bfloat16(kkv[j] * expf(-li));
            vsT[ch + j][t4] = __float2bfloat16(vv[j]);
            scT[t4][ch + j] = __float2bfloat16(ss[j]);   // row t4 = v
            dpart = fmaf(rr[j] * uu[j], kkv[j], dpart);
        }
    }
    dpart += __shfl_xor(dpart, 1);
    dpart += __shfl_xor(dpart, 2);
    if ((tid & 3) == 0) diag[t4] = dpart;
    __syncthreads();        // linc dead; asb may now overwrite uni
    int l15 = lane & 15, l4q = lane >> 4;
    #pragma unroll
    for (int nt = 0; nt < 4; nt++) {
        f32x4_t acc = {};
        if (nt <= wave) {
            #pragma unroll
            for (int kt = 0; kt < 2; kt++) {
                bf16x8_t a = *reinterpret_cast<const bf16x8_t*>(&qs[wave * 16 + l15][kt * 32 + l4q * 8]);
                bf16x8_t bb = *reinterpret_cast<const bf16x8_t*>(&ks[nt * 16 + l15][kt * 32 + l4q * 8]);
                acc = __builtin_amdgcn_mfma_f32_16x16x32_bf16(a, bb, acc, 0, 0, 0);
            }
        }
        #pragma unroll
        for (int q = 0; q < 4; q++) {
            int t = wave * 16 + l4q * 4 + q;
            int tau = nt * 16 + l15;
            float v = (tau < t) ? acc[q] : (tau == t ? diag[t] : 0.f);
            asb[t][tau] = __float2bfloat16(v);
        }
    }
    __syncthreads();
    #pragma unroll
    for (int nt = 0; nt < 4; nt++) {
        f32x4_t acc = {};
        int kmax = (wave >> 1) + 1;
        for (int kt = 0; kt < kmax; kt++) {
            bf16x8_t a = *reinterpret_cast<const bf16x8_t*>(&asb[wave * 16 + l15][kt * 32 + l4q * 8]);
            bf16x8_t bb = *reinterpret_cast<const bf16x8_t*>(&vsT[nt * 16 + l15][kt * 32 + l4q * 8]);
            acc = __builtin_amdgcn_mfma_f32_16x16x32_bf16(a, bb, acc, 0, 0, 0);
        }
        #pragma unroll
        for (int kt = 0; kt < 2; kt++) {
            bf16x8_t a = *reinterpret_cast<const bf16x8_t*>(&qs[wave * 16 + l15][kt * 32 + l4q * 8]);
            bf16x8_t bb = *reinterpret_cast<const bf16x8_t*>(&scT[nt * 16 + l15][kt * 32 + l4q * 8]);
            acc = __builtin_amdgcn_mfma_f32_16x16x32_bf16(a, bb, acc, 0, 0, 0);
        }
        #pragma unroll
        for (int q = 0; q < 4; q++) {
            int t = wave * 16 + l4q * 4 + q;
            y[gbase + (size_t)t * 1024 + nt * 16 + l15] = acc[q];
        }
    }
}

// ---------------------------------------------------------------------------
// GroupNorm per (bt,h) over 64 channels (after /8), *ln_w + ln_b, then *g.
// ---------------------------------------------------------------------------
__global__ __launch_bounds__(256) void gn_mul(const float* __restrict__ y,
                                              const __hip_bfloat16* __restrict__ g,
                                              const float* __restrict__ lnw,
                                              const float* __restrict__ lnb,
                                              __hip_bfloat16* __restrict__ fin) {
    int tid = threadIdx.x;
    int lane = tid & 63;
    int wv = tid >> 6;
    int grp = blockIdx.x * 4 + wv;    // bt*16 + h
    int h = grp & 15;
    size_t idx = (size_t)grp * 64 + lane;
    float val = y[idx] * 0.125f;
    float sum = val, sq = val * val;
    #pragma unroll
    for (int off = 32; off > 0; off >>= 1) {
        sum += __shfl_xor(sum, off, 64);
        sq  += __shfl_xor(sq,  off, 64);
    }
    float mu = sum * (1.f / 64.f);
    float var = sq * (1.f / 64.f) - mu * mu;
    float rs = rsqrtf(var + 1e-5f);
    float o = (val - mu) * rs * lnw[h * 64 + lane] + lnb[h * 64 + lane];
    fin[idx] = __float2bfloat16(o * __bfloat162float(g[idx]));
}

// ---------------------------------------------------------------------------
extern "C" void kernel_launch(void* const* d_in, const int* in_sizes, int n_in,
                              void* d_out, int out_size, void* d_ws, size_t ws_size,
                              hipStream_t stream) {
    (void)in_sizes; (void)n_in; (void)out_size; (void)ws_size;
    const float* x      = (const float*)d_in[0];
    const float* x_maa  = (const float*)d_in[1];
    const float* w_maa  = (const float*)d_in[2];
    const float* k_maa  = (const float*)d_in[3];
    const float* v_maa  = (const float*)d_in[4];
    const float* r_maa  = (const float*)d_in[5];
    const float* g_maa  = (const float*)d_in[6];
    const float* tm_w1  = (const float*)d_in[7];
    const float* tm_w2  = (const float*)d_in[8];
    const float* td_w1  = (const float*)d_in[9];
    const float* td_w2  = (const float*)d_in[10];
    const float* t_dec  = (const float*)d_in[11];
    const float* t_first= (const float*)d_in[12];
    const float* Wr     = (const float*)d_in[13];
    const float* Wk     = (const float*)d_in[14];
    const float* Wv     = (const float*)d_in[15];
    const float* Wg     = (const float*)d_in[16];
    const float* Wo     = (const float*)d_in[17];
    const float* ln_w   = (const float*)d_in[18];
    const float* ln_b   = (const float*)d_in[19];
    float* out = (float*)d_out;

    // Byte allocator, 256B aligned
    char* ws = (char*)d_ws;
    size_t off = 0;
    auto alloc = [&](size_t bytes) -> void* {
        void* p = ws + off;
        off = (off + bytes + 255) & ~(size_t)255;
        return p;
    };
    __hip_bfloat16* mixin = (__hip_bfloat16*)alloc(BTC * 2);  // alias: rb (bf16)
    __hip_bfloat16* mix160b = (__hip_bfloat16*)alloc((size_t)BT * 160 * 2);
    float* wxr    = (float*)alloc(BTC * 4);            // wx -> BcB -> ybuf
    __hip_bfloat16* kxb = (__hip_bfloat16*)alloc(BTC * 2);  // alias: fin
    __hip_bfloat16* vxb = (__hip_bfloat16*)alloc(BTC * 2);
    __hip_bfloat16* rxb = (__hip_bfloat16*)alloc(BTC * 2);  // rxb+gxb -> SbufT (16MB)
    __hip_bfloat16* gxb = (__hip_bfloat16*)alloc(BTC * 2);
    __hip_bfloat16* kb  = (__hip_bfloat16*)alloc(BTC * 2);
    __hip_bfloat16* vb  = (__hip_bfloat16*)alloc(BTC * 2);
    __hip_bfloat16* gb  = (__hip_bfloat16*)alloc(BTC * 2);
    float* wl1 = (float*)alloc((size_t)BT * 64 * 4);   // alias: WtB
    float* lwb = (float*)alloc(BTC * 4);
    __hip_bfloat16* WrT = (__hip_bfloat16*)alloc((size_t)Cn * Cn * 2);
    __hip_bfloat16* WkT = (__hip_bfloat16*)alloc((size_t)Cn * Cn * 2);
    __hip_bfloat16* WvT = (__hip_bfloat16*)alloc((size_t)Cn * Cn * 2);
    __hip_bfloat16* WgT = (__hip_bfloat16*)alloc((size_t)Cn * Cn * 2);
    __hip_bfloat16* WoT = (__hip_bfloat16*)alloc((size_t)Cn * Cn * 2);
    __hip_bfloat16* tmw1T = (__hip_bfloat16*)alloc((size_t)160 * Cn * 2);
    __hip_bfloat16* w2T   = (__hip_bfloat16*)alloc((size_t)Cn * 160 * 2);
    // Big time-shared region (40 MB): lorapart -> d5 -> skpart (disjoint lifetimes)
    char* big = (char*)alloc((size_t)5 * BTC * 2);
    float* lorapart = (float*)big;            // [4][BT*160] f32 (10.5 MB)
    __hip_bfloat16* d5 = (__hip_bfloat16*)big; // [5][BTC] bf16 (40 MB)
    float* skpart = (float*)big;              // [8][BT*64] f32 (8 MB)
    // Aliases (stream-ordered; producers complete before reuse):
    __hip_bfloat16* rb = mixin;    // r projection (mixin dead after LoRA1)
    float* BcB   = wxr;            // chunk contributions (wx dead after splitk)
    float* ybuf  = wxr;            // recurrence out (BcB dead after chunk_scan)
    float* WtB   = wl1;            // chunk decay totals (wl1 dead after decay GEMM)
    float* SbufT = (float*)rxb;    // entry states (transposed), spans rxb+gxb
    __hip_bfloat16* fin = kxb;     // gn output (kxb dead after projections)

    dim3 blk(256);
    // weight transpose+convert
    transp5<<<dim3(32, 32, 5), blk, 0, stream>>>(Wr, Wk, Wv, Wg, Wo,
                                                 WrT, WkT, WvT, WgT, WoT);
    transp_bf16<<<dim3(5, 32), blk, 0, stream>>>(tm_w1, tmw1T, Cn, 160);
    transp_bf16<<<dim3(32, 5), blk, 0, stream>>>(tm_w2, w2T, 160, Cn);
    // token-mix LoRA1 (bf16 MFMA split-K over 4 K-parts, 512 blocks)
    prep_mixin<<<dim3((unsigned)(BTC / 1024)), blk, 0, stream>>>(x, x_maa, mixin);
    gemm_mfma_sk<4><<<dim3(2, 64, 4), blk, 0, stream>>>(mixin, tmw1T, lorapart, BT, 160, Cn);
    splitk_reduce_tanh_bf<4><<<dim3((BT * 160 + 255) / 256), blk, 0, stream>>>(
        lorapart, mix160b, BT * 160, (size_t)BT * 160);
    // deltas: batched MFMA GEMM (z=f) then streaming fuse
    dmix_gemm<<<dim3(64, 8, 5), blk, 0, stream>>>(mix160b, w2T, d5);
    dmix_fuse<<<dim3((unsigned)(BTC / 1024)), blk, 0, stream>>>(x, d5,
                                                                w_maa, k_maa, v_maa, r_maa, g_maa,
                                                                wxr, kxb, vxb, rxb, gxb);
    // projections: ONE grouped dispatch (r,k,v,g), m-fastest grid
    gemm_qkvg<<<dim3(64, 8, 4), blk, 0, stream>>>(rxb, kxb, vxb, gxb,
                                                  WrT, WkT, WvT, WgT,
                                                  rb, kb, vb, gb, BT, Cn, Cn);
    // decay LoRA1 (f32 split-K, 512 blocks) + fused reduce/tanh
    gemm_f32_splitk<8><<<dim3(8, 64), blk, 0, stream>>>(wxr, td_w1, skpart, BT, 64, Cn);
    splitk_reduce_tanh<8><<<dim3(BT * 64 / 256), blk, 0, stream>>>(skpart, wl1, BT * 64,
                                                                   (size_t)BT * 64);
    // decay GEMM2 (f32, precision-sensitive)
    gemm_f32<3><<<dim3(16, 64), blk, 0, stream>>>(wl1, td_w2, lwb, BT, Cn, 64, t_dec);
    // chunked scan (MFMA)
    chunk_summary<<<dim3(Bn * Hn * NC), blk, 0, stream>>>(kb, vb, lwb, BcB, WtB);
    chunk_scan<<<dim3(Bn * Hn * 4), blk, 0, stream>>>(BcB, WtB, SbufT);
    chunk_out<<<dim3(Bn * Hn * NC), blk, 0, stream>>>(rb, kb, vb, lwb, SbufT, t_first, ybuf);
    // epilogue
    gn_mul<<<dim3(BT * Hn / 4), blk, 0, stream>>>(ybuf, gb, ln_w, ln_b, fin);
    gemm_mfma_gl<<<dim3(64, 8), blk, 0, stream>>>(fin, WoT, out, BT, Cn, Cn);
}